// Round 12
// baseline (726.976 us; speedup 1.0000x reference)
//
#include <hip/hip_runtime.h>
#include <cstdint>
#include <cstddef>

// ---------------------------------------------------------------------------
// TransformerMultiViewFusion (MI355X / gfx950), round 19.
//
//  R19 change: explicit software-pipelined weight prefetch.
//   Diagnosis: R15->R18 counters show ffn is load-LATENCY-bound, not
//   throughput-bound (halving bytes R14->R15 only saved 16%; MfmaUtil 31%,
//   VALUBusy 28%, occupancy 24%, VGPR just 84). The asm barrier "memory"
//   clobbers pin weight loads in program order: compiler cannot hoist the
//   next phase's fragment loads above WAITL/WAITV barriers, so every phase
//   boundary eats ~200-400cy of L2 latency at 2-3 waves/SIMD.
//   * ffn v10: pA[2][2]/pB[2][4] double-buffered prefetch (compile-time
//     indices under full unroll): A-step s prefetches s+1; step 7 prefetches
//     phase-B W2; B-step 3 prefetches next hc's W1 — all issued BEFORE the
//     barriers they would otherwise wait behind.
//   * gemm_qkv: B prefetched one kc ahead with STAGE(kc+1); counted wait
//     becomes vmcnt(8) (4 stage + 4 B in flight).
//   * attn_ln: Wo step-0 frags issued at kernel entry (hidden under all of
//     phase 1); loop prefetches one step ahead.
//   Memory layouts, tilings, and all other kernels unchanged from R18.
//
//  Design rules learned (R7-R18):
//   - gload_lds staging port ~16 B/cyc/CU; direct fragment-order vmem ~29.
//   - direct loads must be DISJOINT per wave (1x4 tiling).
//   - per-block weight working set must stay L2-co-resident.
//   - hc rotation helps; scattering a sequential fragment stream hurts.
//   - asm "memory" barriers pin loads: prefetch explicitly across them.
//
//  Workspace: X@0 | QKV@37748736 | Xf@188743680 | WpB@198180864 |
//             Wb@226492416
// ---------------------------------------------------------------------------

typedef __bf16 bf16;
typedef __bf16 bf16x8 __attribute__((ext_vector_type(8)));
typedef __bf16 bf16x4 __attribute__((ext_vector_type(4)));
typedef float  f32x4  __attribute__((ext_vector_type(4)));

__device__ __forceinline__ void async_copy16(const void* g, void* l)
{
    __builtin_amdgcn_global_load_lds(
        (__attribute__((address_space(1))) void*)g,
        (__attribute__((address_space(3))) void*)l,
        16, 0, 0);
}

#define WAITV8_BAR() asm volatile("s_waitcnt vmcnt(8)\ns_barrier" ::: "memory")
#define WAITV4_BAR() asm volatile("s_waitcnt vmcnt(4)\ns_barrier" ::: "memory")
#define WAITV0_BAR() asm volatile("s_waitcnt vmcnt(0)\ns_barrier" ::: "memory")
#define WAITL_BAR()  asm volatile("s_waitcnt lgkmcnt(0)\ns_barrier" ::: "memory")

// --------------------------------------------------------------------------
// all 5 weight packs in one launch. 1589248 = 6208*256 exactly.
// Wqkv -> fragment order: frag = (kc*2+kk)*48 + nt (nt 0..47).
// Wo   -> fragment order: frag = s*16 + nt (s 0..7, nt 0..15).
// W1   -> fragment order: frag = ((hc*4+q)*2+kk)*8 + nt.
// W2   -> fragment order: frag = (hc*4+q)*16 + nt.
// --------------------------------------------------------------------------
__global__ void pack_all_k(const float* __restrict__ s0, const float* __restrict__ s1,
                           const float* __restrict__ s2, const float* __restrict__ s3,
                           const float* __restrict__ s4,
                           bf16* __restrict__ d0, bf16* __restrict__ d1,
                           bf16* __restrict__ d2, bf16* __restrict__ d3,
                           bf16* __restrict__ d4)
{
    const int i = blockIdx.x * 256 + threadIdx.x;
    if (i < 393216) {
        const int j = i;
        const int l = (j >= 196608) ? 1 : 0;
        const int r = j - l * 196608;
        const int e     = r & 7;
        const int idx16 = r >> 3;
        const int lane  = idx16 & 63;
        const int l16   = lane & 15;
        const int quad  = lane >> 4;
        const int frag  = idx16 >> 6;        // 0..383
        const int ckk   = frag / 48;
        const int nt    = frag - ckk * 48;
        const int kc    = ckk >> 1, kk = ckk & 1;
        const int n     = nt * 16 + l16;
        const int k     = kc * 64 + (kk * 4 + quad) * 8 + e;
        d0[j] = (bf16)s0[l * 196608 + n * 256 + k];
    } else if (i < 524288) {
        const int j = i - 393216;
        const int l = j >> 16, r = j & 65535;
        const int e     = r & 7;
        const int idx16 = r >> 3;
        const int lane  = idx16 & 63;
        const int l16   = lane & 15;
        const int quad  = lane >> 4;
        const int frag  = idx16 >> 6;        // 0..127
        const int s     = frag >> 4, nt = frag & 15;
        const int n     = nt * 16 + l16;
        const int k     = s * 32 + quad * 8 + e;
        d1[j] = (bf16)s1[l * 65536 + n * 256 + k];
    } else if (i < 1048576) {
        const int j = i - 524288;
        const int l = j >> 18, r = j & 262143;
        const int e     = r & 7;
        const int idx16 = r >> 3;
        const int l16   = idx16 & 15;
        const int quad  = (idx16 >> 4) & 3;
        const int nt    = (idx16 >> 6) & 7;
        const int kk    = (idx16 >> 9) & 1;
        const int q     = (idx16 >> 10) & 3;
        const int hc    = idx16 >> 12;
        const int row   = hc * 128 + nt * 16 + l16;
        const int k     = q * 64 + (kk * 4 + quad) * 8 + e;
        d2[j] = (bf16)s2[l * 262144 + row * 256 + k];
    } else if (i < 1572864) {
        const int j = i - 1048576;
        const int l = j >> 18, r = j & 262143;
        const int e     = r & 7;
        const int idx16 = r >> 3;
        const int l16   = idx16 & 15;
        const int quad  = (idx16 >> 4) & 3;
        const int nt    = (idx16 >> 6) & 15;
        const int q     = (idx16 >> 10) & 3;
        const int hc    = idx16 >> 12;
        const int n     = nt * 16 + l16;
        const int k     = hc * 128 + q * 32 + quad * 8 + e;
        d3[j] = (bf16)s3[l * 262144 + n * 1024 + k];
    }
    else                  d4[i - 1572864] = (bf16)s4[i - 1572864];
}

// --------------------------------------------------------------------------
// feat transpose-pack: Xf[t][c] = (bf16)feat[cam][b][c][hw]
// --------------------------------------------------------------------------
__global__ __launch_bounds__(256) void feat_pack_k(const float* __restrict__ feat,
                                                   bf16* __restrict__ Xf)
{
    __shared__ float ft[64][68];

    const int tid  = threadIdx.x;
    const int camb = blockIdx.y;
    const int cam  = camb >> 1;
    const int b    = camb & 1;
    const int hw0  = blockIdx.x * 64;

    const float* fb = feat + (size_t)camb * 64 * 9216 + hw0;
#pragma unroll
    for (int rep = 0; rep < 16; ++rep) {
        const int idx = rep * 256 + tid;
        const int c = idx >> 6, p = idx & 63;
        ft[p][c] = fb[(size_t)c * 9216 + p];
    }
    __syncthreads();

    const int pbase = b * 9216 + hw0;
#pragma unroll
    for (int rep = 0; rep < 2; ++rep) {
        const int idx = rep * 256 + tid;
        const int p = idx >> 3, cc = idx & 7;
        const f32x4 a = *(const f32x4*)(&ft[p][cc * 8]);
        const f32x4 c4 = *(const f32x4*)(&ft[p][cc * 8 + 4]);
        bf16x8 v;
#pragma unroll
        for (int i = 0; i < 4; ++i) { v[i] = (bf16)a[i]; v[4 + i] = (bf16)c4[i]; }
        const size_t t = (size_t)(pbase + p) * 4 + cam;
        *(bf16x8*)(Xf + t * 64 + cc * 8) = v;
    }
}

// --------------------------------------------------------------------------
// GEMM-BT v2 (Wp projection only): 128x128 tile, counted vmcnt ping-pong.
// --------------------------------------------------------------------------
template <bool RELU>
__global__ __launch_bounds__(256, 2) void gemm_bt(
    const bf16* __restrict__ A, const bf16* __restrict__ B,
    const float* __restrict__ bias, bf16* __restrict__ C,
    int N, int K)
{
    __shared__ __align__(16) char smem[65536];

    const int tid  = threadIdx.x;
    const int lane = tid & 63;
    const int wv   = tid >> 6;
    const int wm   = wv >> 1;
    const int wn   = wv & 1;
    const int bm   = blockIdx.y * 128;
    const int bn   = blockIdx.x * 128;

    const int r8  = lane >> 3;
    const int p8  = lane & 7;
    const int gch = p8 ^ r8;

    const int quad = lane >> 4;
    const int l16  = lane & 15;

    f32x4 acc[4][4] = {};
    const int nk = K >> 6;

    auto STAGE = [&](int kc, char* base) {
#pragma unroll
        for (int inst = 0; inst < 4; ++inst) {
            const int row = wv * 32 + inst * 8 + r8;
            async_copy16(A + (size_t)(bm + row) * K + (kc * 64 + gch * 8),
                         base + (wv * 4 + inst) * 1024);
            async_copy16(B + (size_t)(bn + row) * K + (kc * 64 + gch * 8),
                         base + 16384 + (wv * 4 + inst) * 1024);
        }
    };

    STAGE(0, smem);

#pragma unroll 1
    for (int kc = 0; kc < nk; ++kc) {
        const char* cur = smem + (size_t)(kc & 1) * 32768;
        if (kc + 1 < nk) {
            STAGE(kc + 1, smem + (size_t)((kc + 1) & 1) * 32768);
            WAITV8_BAR();
        } else {
            WAITV0_BAR();
        }

#pragma unroll
        for (int kk = 0; kk < 2; ++kk) {
            bf16x8 af[4], bfr[4];
            const int lch = kk * 4 + quad;
#pragma unroll
            for (int i = 0; i < 4; ++i) {
                const int m = wm * 64 + i * 16 + l16;
                af[i] = *(const bf16x8*)(cur + (m * 8 + (lch ^ (m & 7))) * 16);
                const int n = wn * 64 + i * 16 + l16;
                bfr[i] = *(const bf16x8*)(cur + 16384 + (n * 8 + (lch ^ (n & 7))) * 16);
            }
            __builtin_amdgcn_s_setprio(1);
#pragma unroll
            for (int i = 0; i < 4; ++i)
#pragma unroll
                for (int j = 0; j < 4; ++j)
                    acc[i][j] = __builtin_amdgcn_mfma_f32_16x16x32_bf16(
                        af[i], bfr[j], acc[i][j], 0, 0, 0);
            __builtin_amdgcn_s_setprio(0);
        }
        WAITL_BAR();
    }

#pragma unroll
    for (int j = 0; j < 4; ++j) {
        const int n = bn + wn * 64 + j * 16 + l16;
        const float bv = bias[n];
#pragma unroll
        for (int i = 0; i < 4; ++i) {
            const int mb = bm + wm * 64 + i * 16 + quad * 4;
#pragma unroll
            for (int r = 0; r < 4; ++r) {
                float v = acc[i][j][r] + bv;
                if (RELU) v = fmaxf(v, 0.f);
                C[(size_t)(mb + r) * N + n] = (bf16)v;
            }
        }
    }
}

// --------------------------------------------------------------------------
// QKV GEMM (R18 + B prefetch): C[73728,768] = X @ WqkvP^T + bqkv.
// grid (6,576). 4 waves 1x4. B prefetched one kc ahead (pB[2][4]); counted
// wait vmcnt(8) = 4 stage + 4 B in flight. LDS 32KB -> 3 blocks/CU.
// --------------------------------------------------------------------------
__global__ __launch_bounds__(256, 3) void gemm_qkv_k(
    const bf16* __restrict__ A, const bf16* __restrict__ BP,
    const float* __restrict__ bias, bf16* __restrict__ C)
{
    __shared__ __align__(16) char smem[32768];

    const int tid  = threadIdx.x;
    const int lane = tid & 63;
    const int wv   = tid >> 6;
    const int wn   = wv;               // 1x4 column slice
    const int bm   = blockIdx.y * 128;
    const int bn   = blockIdx.x * 128;
    const int ntb  = blockIdx.x * 8;   // base column fragment

    const int r8  = lane >> 3;
    const int p8  = lane & 7;
    const int gch = p8 ^ r8;
    const int quad = lane >> 4;
    const int l16  = lane & 15;

    f32x4 acc[8][2] = {};

    auto STAGE = [&](int kc, char* base) {
#pragma unroll
        for (int inst = 0; inst < 4; ++inst) {
            const int row = wv * 32 + inst * 8 + r8;
            async_copy16(A + (size_t)(bm + row) * 256 + (kc * 64 + gch * 8),
                         base + (wv * 4 + inst) * 1024);
        }
    };

    bf16x8 pB[2][4];
    auto LOADB = [&](int kc, int buf) {
#pragma unroll
        for (int kk = 0; kk < 2; ++kk)
#pragma unroll
            for (int j = 0; j < 2; ++j)
                pB[buf][kk * 2 + j] = *(const bf16x8*)(BP +
                    ((size_t)((kc * 2 + kk) * 48 + ntb + wn * 2 + j)) * 512
                    + lane * 8);
    };

    STAGE(0, smem);
    LOADB(0, 0);

#pragma unroll
    for (int kc = 0; kc < 4; ++kc) {
        const char* cur = smem + (size_t)(kc & 1) * 16384;
        if (kc < 3) {
            STAGE(kc + 1, smem + (size_t)((kc + 1) & 1) * 16384);
            LOADB(kc + 1, (kc + 1) & 1);
            WAITV8_BAR();
        } else {
            WAITV0_BAR();
        }

#pragma unroll
        for (int kk = 0; kk < 2; ++kk) {
            const int lch = kk * 4 + quad;
            bf16x8 af[8];
#pragma unroll
            for (int i = 0; i < 8; ++i) {
                const int m = i * 16 + l16;
                af[i] = *(const bf16x8*)(cur + (m * 8 + (lch ^ (m & 7))) * 16);
            }
            __builtin_amdgcn_s_setprio(1);
#pragma unroll
            for (int i = 0; i < 8; ++i)
#pragma unroll
                for (int j = 0; j < 2; ++j)
                    acc[i][j] = __builtin_amdgcn_mfma_f32_16x16x32_bf16(
                        af[i], pB[kc & 1][kk * 2 + j], acc[i][j], 0, 0, 0);
            __builtin_amdgcn_s_setprio(0);
        }
        WAITL_BAR();
    }

#pragma unroll
    for (int j = 0; j < 2; ++j) {
        const int n = bn + wn * 32 + j * 16 + l16;
        const float bv = bias[n];
#pragma unroll
        for (int i = 0; i < 8; ++i) {
            const int mb = bm + i * 16 + quad * 4;
#pragma unroll
            for (int r = 0; r < 4; ++r)
                C[(size_t)(mb + r) * 768 + n] = (bf16)(acc[i][j][r] + bv);
        }
    }
}

// --------------------------------------------------------------------------
// Fused attention + Wo-GEMM + bias + residual + LayerNorm (R18 + prefetch).
// Block = 64 rows = 16 sequences, 256 threads (4 waves), 3 blocks/CU.
// Wo step-0 frags issued at kernel entry (hidden under phase 1); loop
// prefetches one step ahead. LDS: SAs 32K | red[64][4] 2K = 34K.
// --------------------------------------------------------------------------
__global__ __launch_bounds__(256, 3) void attn_ln_k(
    const bf16* __restrict__ QKV, const bf16* __restrict__ WoP,
    const float* __restrict__ bias, const bf16* __restrict__ Xres,
    const float* __restrict__ gam, const float* __restrict__ bet,
    bf16* __restrict__ Xout)
{
    __shared__ __align__(16) char smem[34816];
    bf16* SAs = (bf16*)smem;                      // 64 rows x 32 chunks (32K)
    float2 (*red)[4] = (float2 (*)[4])(void*)(smem + 32768);   // [64][4]

    const int tid  = threadIdx.x;
    const int lane = tid & 63;
    const int wv   = tid >> 6;
    const int wn   = wv;               // phase-2 column slice
    const int quad = lane >> 4;
    const int l16  = lane & 15;
    const int bm   = blockIdx.x * 64;
    const int rot  = (blockIdx.x >> 3) & 7;

    // prefetch Wo step-0 fragments at entry — retires under phase 1
    bf16x8 pW[2][4];
#pragma unroll
    for (int j = 0; j < 4; ++j)
        pW[0][j] = *(const bf16x8*)(WoP +
            ((size_t)(rot * 16 + wn * 4 + j)) * 512 + lane * 8);

    // ================= phase 1: register attention, 4 seqs/wave ============
    {
        const int hh = lane >> 3;        // head 0..7
        const int cg = lane & 7;         // 4-col group 0..7
        const int s0 = blockIdx.x * 16;
        const float SCALE = 0.17677669529663687f;

#pragma unroll
        for (int g = 0; g < 4; ++g) {
            const int seq = s0 + g * 4 + wv;
            const bf16* bse = QKV + (size_t)seq * 3072 + hh * 32 + cg * 4;

            float qf[4][4], kf[4][4], vf[4][4];
#pragma unroll
            for (int i = 0; i < 4; ++i) {
                const bf16x4 qb = *(const bf16x4*)(bse + i * 768);
                const bf16x4 kb = *(const bf16x4*)(bse + i * 768 + 256);
                const bf16x4 vb = *(const bf16x4*)(bse + i * 768 + 512);
#pragma unroll
                for (int d = 0; d < 4; ++d) {
                    qf[i][d] = (float)qb[d];
                    kf[i][d] = (float)kb[d];
                    vf[i][d] = (float)vb[d];
                }
            }

            float sc[4][4];
#pragma unroll
            for (int i = 0; i < 4; ++i)
#pragma unroll
                for (int j = 0; j < 4; ++j)
                    sc[i][j] = qf[i][0] * kf[j][0] + qf[i][1] * kf[j][1]
                             + qf[i][2] * kf[j][2] + qf[i][3] * kf[j][3];

#pragma unroll
            for (int msk = 1; msk <= 4; msk <<= 1)
#pragma unroll
                for (int i = 0; i < 4; ++i)
#pragma unroll
                    for (int j = 0; j < 4; ++j)
                        sc[i][j] += __shfl_xor(sc[i][j], msk, 64);

#pragma unroll
            for (int i = 0; i < 4; ++i) {
                const float v0 = sc[i][0] * SCALE, v1 = sc[i][1] * SCALE;
                const float v2 = sc[i][2] * SCALE, v3 = sc[i][3] * SCALE;
                const float mx = fmaxf(fmaxf(v0, v1), fmaxf(v2, v3));
                const float e0 = expf(v0 - mx), e1 = expf(v1 - mx);
                const float e2 = expf(v2 - mx), e3 = expf(v3 - mx);
                const float inv = 1.f / (e0 + e1 + e2 + e3);
                sc[i][0] = e0 * inv; sc[i][1] = e1 * inv;
                sc[i][2] = e2 * inv; sc[i][3] = e3 * inv;
            }

#pragma unroll
            for (int i = 0; i < 4; ++i) {
                bf16x4 ov;
#pragma unroll
                for (int d = 0; d < 4; ++d) {
                    const float o = sc[i][0] * vf[0][d] + sc[i][1] * vf[1][d]
                                  + sc[i][2] * vf[2][d] + sc[i][3] * vf[3][d];
                    ov[d] = (bf16)o;
                }
                const int m  = (g * 4 + wv) * 4 + i;
                const int gc = lane >> 1;
                const int sl = (gc & 24) | ((gc ^ m) & 7);
                *(bf16x4*)((char*)SAs + (m * 32 + sl) * 16 + (lane & 1) * 8) = ov;
            }
        }
    }
    __syncthreads();   // SAs complete

    // ================= phase 2: Wo GEMM, 8 k-steps, prefetched direct-B ====
    f32x4 acc[4][4] = {};

#pragma unroll
    for (int s = 0; s < 8; ++s) {
        const int sr = (s + rot) & 7;
        const int gc = sr * 4 + quad;
        if (s < 7) {
            const int srn = (s + 1 + rot) & 7;
#pragma unroll
            for (int j = 0; j < 4; ++j)
                pW[(s + 1) & 1][j] = *(const bf16x8*)(WoP +
                    ((size_t)(srn * 16 + wn * 4 + j)) * 512 + lane * 8);
        }
        bf16x8 af[4];
#pragma unroll
        for (int i = 0; i < 4; ++i) {
            const int m  = i * 16 + l16;
            const int sl = (gc & 24) | ((gc ^ m) & 7);
            af[i] = *(const bf16x8*)((const char*)SAs + (m * 32 + sl) * 16);
        }
        __builtin_amdgcn_s_setprio(1);
#pragma unroll
        for (int i = 0; i < 4; ++i)
#pragma unroll
            for (int j = 0; j < 4; ++j)
                acc[i][j] = __builtin_amdgcn_mfma_f32_16x16x32_bf16(
                    af[i], pW[s & 1][j], acc[i][j], 0, 0, 0);
        __builtin_amdgcn_s_setprio(0);
    }

    // ---- epilogue: bias + residual (global) + LayerNorm; red[64][4]
    float bv[4], gv[4], bev[4];
#pragma unroll
    for (int j = 0; j < 4; ++j) {
        const int n = wn * 64 + j * 16 + l16;
        bv[j] = bias[n]; gv[j] = gam[n]; bev[j] = bet[n];
    }

#pragma unroll
    for (int i = 0; i < 4; ++i) {
#pragma unroll
        for (int r = 0; r < 4; ++r) {
            const int rl = i * 16 + quad * 4 + r;
            const size_t row = (size_t)(bm + rl);
            float s1 = 0.f, s2 = 0.f;
#pragma unroll
            for (int j = 0; j < 4; ++j) {
                const int n = wn * 64 + j * 16 + l16;
                const float v = acc[i][j][r] + bv[j] + (float)Xres[row * 256 + n];
                acc[i][j][r] = v;
                s1 += v; s2 += v * v;
            }
#pragma unroll
            for (int off = 1; off < 16; off <<= 1) {
                s1 += __shfl_xor(s1, off, 64);
                s2 += __shfl_xor(s2, off, 64);
            }
            if (l16 == 0) red[rl][wn] = make_float2(s1, s2);
        }
    }
    __syncthreads();

#pragma unroll
    for (int i = 0; i < 4; ++i) {
#pragma unroll
        for (int r = 0; r < 4; ++r) {
            const int rl = i * 16 + quad * 4 + r;
            const float2 p0 = red[rl][0], p1 = red[rl][1];
            const float2 p2 = red[rl][2], p3 = red[rl][3];
            const float mu  = (p0.x + p1.x + p2.x + p3.x) * (1.f / 256.f);
            const float ex2 = (p0.y + p1.y + p2.y + p3.y) * (1.f / 256.f);
            const float rstd = rsqrtf(fmaxf(ex2 - mu * mu, 0.f) + 1e-5f);
            const size_t row = (size_t)(bm + rl);
#pragma unroll
            for (int j = 0; j < 4; ++j) {
                const int n = wn * 64 + j * 16 + l16;
                Xout[row * 256 + n] = (bf16)((acc[i][j][r] - mu) * rstd * gv[j] + bev[j]);
            }
        }
    }
}

// --------------------------------------------------------------------------
// Fused FFN v10 (R15 + explicit prefetch): 64-row tile, grid 1152, 4 waves
// 1x4, 3 blocks/CU. pA[2][2]/pB[2][4] double-buffered weight prefetch:
// A-step s prefetches s+1; step7 prefetches phase-B W2 (before Ts barrier);
// B-step3 prefetches next hc W1 (before closing barrier).
// LDS: Xs 32K | Ts 16K (red[64][4] aliases) = 48KB.
// --------------------------------------------------------------------------
__global__ __launch_bounds__(256, 3) void ffn_fused_k(
    const bf16* __restrict__ X,
    const bf16* __restrict__ W1P, const float* __restrict__ b1,
    const bf16* __restrict__ W2P, const float* __restrict__ b2,
    const float* __restrict__ gam, const float* __restrict__ bet,
    bf16* __restrict__ Xout)
{
    __shared__ __align__(16) char smem[49152];
    bf16* Xs = (bf16*)smem;                       // 64 x 256 (32 slots/row)
    bf16* Ts = (bf16*)(smem + 32768);             // 64 x 128 (16 slots/row)
    float2 (*red)[4] = (float2 (*)[4])(void*)(smem + 32768);   // aliases Ts

    const int tid  = threadIdx.x;
    const int lane = tid & 63;
    const int wn   = tid >> 6;          // 0..3: wave's column slice
    const int quad = lane >> 4;
    const int l16  = lane & 15;
    const int bm   = blockIdx.x * 64;
    const int rot  = (blockIdx.x >> 3) & 7;

    // prologue: stage Xs once + prefetch first W1 step (hc=0 -> hcr=rot)
#pragma unroll
    for (int it = 0; it < 8; ++it) {
        const int L = it * 256 + tid;
        const int row = L >> 5, slot = L & 31;
        const int gch = (slot & 24) | ((slot ^ row) & 7);
        async_copy16(X + (size_t)(bm + row) * 256 + gch * 8,
                     (char*)Xs + (size_t)L * 16);
    }

    bf16x8 pA[2][2], pB[2][4];
#pragma unroll
    for (int j = 0; j < 2; ++j)
        pA[0][j] = *(const bf16x8*)(W1P +
            ((size_t)((rot * 4 * 2) * 8) + wn * 2 + j) * 512 + lane * 8);

    WAITV0_BAR();

    f32x4 acc2[4][4] = {};

#pragma unroll 1
    for (int hc = 0; hc < 8; ++hc) {
        const int hcr = (hc + rot) & 7;
        float b1v[2];
#pragma unroll
        for (int j = 0; j < 2; ++j)
            b1v[j] = b1[hcr * 128 + wn * 32 + j * 16 + l16];

        f32x4 accA[4][2] = {};

        // ---- phase A: accA = Xs @ W1c^T; prefetch s+1 / first W2.
#pragma unroll
        for (int s = 0; s < 8; ++s) {   // q = s>>1, kk = s&1
            const int q  = s >> 1;
            const int kk = s & 1;
            if (s < 7) {
                const int q2 = (s + 1) >> 1, kk2 = (s + 1) & 1;
#pragma unroll
                for (int j = 0; j < 2; ++j)
                    pA[(s + 1) & 1][j] = *(const bf16x8*)(W1P +
                        ((size_t)(((hcr * 4 + q2) * 2 + kk2) * 8) + wn * 2 + j) * 512
                        + lane * 8);
            } else {
#pragma unroll
                for (int j = 0; j < 4; ++j)
                    pB[0][j] = *(const bf16x8*)(W2P +
                        ((size_t)((hcr * 4) * 16) + wn * 4 + j) * 512 + lane * 8);
            }
            const int ch = kk * 4 + quad;
            const int gc = q * 8 + ch;
            bf16x8 af[4];
#pragma unroll
            for (int i = 0; i < 4; ++i) {
                const int m  = i * 16 + l16;
                const int sl = (gc & 24) | ((gc ^ m) & 7);
                af[i] = *(const bf16x8*)((const char*)Xs + (m * 32 + sl) * 16);
            }
            __builtin_amdgcn_s_setprio(1);
#pragma unroll
            for (int i = 0; i < 4; ++i)
#pragma unroll
                for (int j = 0; j < 2; ++j)
                    accA[i][j] = __builtin_amdgcn_mfma_f32_16x16x32_bf16(
                        af[i], pA[s & 1][j], accA[i][j], 0, 0, 0);
            __builtin_amdgcn_s_setprio(0);
        }

        // ---- Ts = relu(accA + b1)  (wave writes cols wn*32..+31)
#pragma unroll
        for (int j = 0; j < 2; ++j) {
            const int h  = wn * 32 + j * 16 + l16;
            const float bb = b1v[j];
            const int g  = h >> 3;
#pragma unroll
            for (int i = 0; i < 4; ++i)
#pragma unroll
                for (int r = 0; r < 4; ++r) {
                    const int m  = i * 16 + quad * 4 + r;
                    const int sl = (g & 8) | ((g ^ m) & 7);
                    const float v = fmaxf(accA[i][j][r] + bb, 0.f);
                    *((bf16*)((char*)Ts + (m * 16 + sl) * 16 + (h & 7) * 2)) = (bf16)v;
                }
        }
        WAITL_BAR();      // Ts writes visible (lgkm only — no vmem drain)

        // ---- phase B: acc2 += Ts @ W2c^T; prefetch s2+1 / next-hc W1.
#pragma unroll
        for (int s2 = 0; s2 < 4; ++s2) {
            if (s2 < 3) {
#pragma unroll
                for (int j = 0; j < 4; ++j)
                    pB[(s2 + 1) & 1][j] = *(const bf16x8*)(W2P +
                        ((size_t)((hcr * 4 + s2 + 1) * 16) + wn * 4 + j) * 512
                        + lane * 8);
            } else if (hc < 7) {
                const int hcn = (hc + 1 + rot) & 7;
#pragma unroll
                for (int j = 0; j < 2; ++j)
                    pA[0][j] = *(const bf16x8*)(W1P +
                        ((size_t)((hcn * 4 * 2) * 8) + wn * 2 + j) * 512 + lane * 8);
            }
            const int tc = s2 * 4 + quad;
            bf16x8 af[4];
#pragma unroll
            for (int i = 0; i < 4; ++i) {
                const int m  = i * 16 + l16;
                const int sl = (tc & 8) | ((tc ^ m) & 7);
                af[i] = *(const bf16x8*)((const char*)Ts + (m * 16 + sl) * 16);
            }
            __builtin_amdgcn_s_setprio(1);
#pragma unroll
            for (int i = 0; i < 4; ++i)
#pragma unroll
                for (int j = 0; j < 4; ++j)
                    acc2[i][j] = __builtin_amdgcn_mfma_f32_16x16x32_bf16(
                        af[i], pB[s2 & 1][j], acc2[i][j], 0, 0, 0);
            __builtin_amdgcn_s_setprio(0);
        }
        WAITL_BAR();      // phase-B Ts reads done before next hc overwrites
    }

    // ---- epilogue: bias + residual (from Xs) + LayerNorm
    float bv[4], gv[4], bev[4];
#pragma unroll
    for (int j = 0; j < 4; ++j) {
        const int n = wn * 64 + j * 16 + l16;
        bv[j] = b2[n]; gv[j] = gam[n]; bev[j] = bet[n];
    }

#pragma unroll
    for (int i = 0; i < 4; ++i) {
#pragma unroll
        for (int r = 0; r < 4; ++r) {
            const int rl = i * 16 + quad * 4 + r;
            float s1 = 0.f, s2 = 0.f;
#pragma unroll
            for (int j = 0; j < 4; ++j) {
                const int n  = wn * 64 + j * 16 + l16;
                const int gc = n >> 3;
                const int sl = (gc & 24) | ((gc ^ rl) & 7);
                const float xr = (float)*((const bf16*)((const char*)Xs +
                                   (rl * 32 + sl) * 16 + (n & 7) * 2));
                const float v = acc2[i][j][r] + bv[j] + xr;
                acc2[i][j][r] = v;
                s1 += v; s2 += v * v;
            }
#pragma unroll
            for (int off = 1; off < 16; off <<= 1) {
                s1 += __shfl_xor(s1, off, 64);
                s2 += __shfl_xor(s2, off, 64);
            }
            if (l16 == 0) red[rl][wn] = make_float2(s1, s2);
        }
    }
    __syncthreads();

#pragma unroll
    for (int i = 0; i < 4; ++i) {
#pragma unroll
        for (int r = 0; r < 4; ++r) {
            const int rl = i * 16 + quad * 4 + r;
            const float2 p0 = red[rl][0], p1 = red[rl][1];
            const float2 p2 = red[rl][2], p3 = red[rl][3];
            const float mu  = (p0.x + p1.x + p2.x + p3.x) * (1.f / 256.f);
            const float ex2 = (p0.y + p1.y + p2.y + p3.y) * (1.f / 256.f);
            const float rstd = rsqrtf(fmaxf(ex2 - mu * mu, 0.f) + 1e-5f);
            const size_t row = (size_t)(bm + rl);
#pragma unroll
            for (int j = 0; j < 4; ++j) {
                const int n = wn * 64 + j * 16 + l16;
                Xout[row * 256 + n] = (bf16)((acc2[i][j][r] - mu) * rstd * gv[j] + bev[j]);
            }
        }
    }
}

// --------------------------------------------------------------------------
// out[b][c][hw] = sum_e (mean_cam X[p*4+cam][e]) * Wout[c][e] + bout[c]
// --------------------------------------------------------------------------
__global__ __launch_bounds__(256) void out_proj_k(const bf16* __restrict__ X,
                                                  const float* __restrict__ Wout,
                                                  const float* __restrict__ bout,
                                                  float* __restrict__ out)
{
    __shared__ float fused[16][260];
    const int tid = threadIdx.x;
    const int p0  = blockIdx.x * 16;

#pragma unroll
    for (int it = 0; it < 16; ++it) {
        const int idx = it * 256 + tid;
        const int pix = idx >> 8, e = idx & 255;
        const size_t base = (size_t)(p0 + pix) * 1024 + e;
        const float s = (float)X[base] + (float)X[base + 256] +
                        (float)X[base + 512] + (float)X[base + 768];
        fused[pix][e] = s * 0.25f;
    }
    __syncthreads();

    const int pix = tid & 15;
    const int c0  = tid >> 4;
    const int p   = p0 + pix;
    const int b   = p / 9216;
    const int hw  = p % 9216;
#pragma unroll
    for (int it = 0; it < 4; ++it) {
        const int c = it * 16 + c0;
        const float* w = Wout + c * 256;
        float acc = bout[c];
#pragma unroll 8
        for (int e = 0; e < 256; ++e) acc += fused[pix][e] * w[e];
        out[((size_t)b * 64 + c) * 9216 + hw] = acc;
    }
}

// --------------------------------------------------------------------------
extern "C" void kernel_launch(void* const* d_in, const int* in_sizes, int n_in,
                              void* d_out, int out_size, void* d_ws, size_t ws_size,
                              hipStream_t stream)
{
    const float* features = (const float*)d_in[0];
    const float* Wp   = (const float*)d_in[1];
    const float* bp   = (const float*)d_in[2];
    const float* Wqkv = (const float*)d_in[3];
    const float* bqkv = (const float*)d_in[4];
    const float* Wo   = (const float*)d_in[5];
    const float* bo   = (const float*)d_in[6];
    const float* W1   = (const float*)d_in[7];
    const float* b1   = (const float*)d_in[8];
    const float* W2   = (const float*)d_in[9];
    const float* b2   = (const float*)d_in[10];
    const float* g1   = (const float*)d_in[11];
    const float* be1  = (const float*)d_in[12];
    const float* g2   = (const float*)d_in[13];
    const float* be2  = (const float*)d_in[14];
    const float* Wout = (const float*)d_in[15];
    const float* bout = (const float*)d_in[16];
    float* out = (float*)d_out;

    char* ws = (char*)d_ws;
    bf16* X   = (bf16*)(ws);                    // 73728*256
    bf16* QKV = (bf16*)(ws + 37748736ull);      // 73728*768
    bf16* Xf  = (bf16*)(ws + 188743680ull);     // 73728*64
    bf16* WpB = (bf16*)(ws + 198180864ull);     // 256*64
    bf16* Wb  = (bf16*)(ws + 226492416ull);     // packed bf16 weights

    bf16* WqkvB = Wb;                  // 2 x 768*256 (fragment order)
    bf16* WoB   = Wb + 393216;         // 2 x 256*256 (fragment order)
    bf16* W1B   = Wb + 524288;         // 2 x 1024*256 (fragment order)
    bf16* W2B   = Wb + 1048576;        // 2 x 256*1024 (fragment order)

    pack_all_k<<<6208, 256, 0, stream>>>(Wqkv, Wo, W1, W2, Wp,
                                         WqkvB, WoB, W1B, W2B, WpB);

    feat_pack_k<<<dim3(144, 8), 256, 0, stream>>>(features, Xf);
    gemm_bt<false><<<dim3(2, 576), 256, 0, stream>>>(Xf, WpB, bp, X, 256, 64);

    for (int l = 0; l < 2; ++l) {
        gemm_qkv_k<<<dim3(6, 576), 256, 0, stream>>>(
            X, WqkvB + l * 196608, bqkv + l * 768, QKV);
        attn_ln_k<<<1152, 256, 0, stream>>>(
            QKV, WoB + l * 65536, bo + l * 256, X,
            g1 + l * 256, be1 + l * 256, X);
        ffn_fused_k<<<1152, 256, 0, stream>>>(
            X, W1B + l * 262144, b1 + l * 1024,
            W2B + l * 262144, b2 + l * 256,
            g2 + l * 256, be2 + l * 256, X);
    }

    out_proj_k<<<1152, 256, 0, stream>>>(X, Wout, bout, out);
}

// Round 13
// 572.278 us; speedup vs baseline: 1.2703x; 1.2703x over previous
//
#include <hip/hip_runtime.h>
#include <cstdint>
#include <cstddef>

// ---------------------------------------------------------------------------
// TransformerMultiViewFusion (MI355X / gfx950), round 20 = R18 exact revert.
//
//  R19 post-mortem: explicit cross-barrier prefetch regs (pA/pB) forced
//  scratch rematerialization under the VGPR cap -> FETCH 32->136MB, ffn
//  107->192us. REVERTED. Phase A was already barrier-free; the compiler
//  already pipelines W1 loads. R18 (570.3us) is the locked best-known state.
//
//  Design rules learned (R7-R19):
//   - gload_lds staging port ~16 B/cyc/CU; direct fragment-order vmem ~29.
//   - direct loads must be DISJOINT per wave (1x4 tiling).
//   - per-block weight working set must stay L2-co-resident; keep column
//     slices interleaved across the dispatch.
//   - hc rotation helps; scattering a sequential fragment stream hurts.
//   - no explicit cross-barrier prefetch registers: compiler spills them.
//
//  Workspace: X@0 | QKV@37748736 | Xf@188743680 | WpB@198180864 |
//             Wb@226492416
// ---------------------------------------------------------------------------

typedef __bf16 bf16;
typedef __bf16 bf16x8 __attribute__((ext_vector_type(8)));
typedef __bf16 bf16x4 __attribute__((ext_vector_type(4)));
typedef float  f32x4  __attribute__((ext_vector_type(4)));

__device__ __forceinline__ void async_copy16(const void* g, void* l)
{
    __builtin_amdgcn_global_load_lds(
        (__attribute__((address_space(1))) void*)g,
        (__attribute__((address_space(3))) void*)l,
        16, 0, 0);
}

#define WAITV8_BAR() asm volatile("s_waitcnt vmcnt(8)\ns_barrier" ::: "memory")
#define WAITV4_BAR() asm volatile("s_waitcnt vmcnt(4)\ns_barrier" ::: "memory")
#define WAITV0_BAR() asm volatile("s_waitcnt vmcnt(0)\ns_barrier" ::: "memory")
#define WAITL_BAR()  asm volatile("s_waitcnt lgkmcnt(0)\ns_barrier" ::: "memory")

// --------------------------------------------------------------------------
// all 5 weight packs in one launch. 1589248 = 6208*256 exactly.
// Wqkv -> fragment order: frag = (kc*2+kk)*48 + nt (nt 0..47).
// Wo   -> fragment order: frag = s*16 + nt (s 0..7, nt 0..15).
// W1   -> fragment order: frag = ((hc*4+q)*2+kk)*8 + nt.
// W2   -> fragment order: frag = (hc*4+q)*16 + nt.
// --------------------------------------------------------------------------
__global__ void pack_all_k(const float* __restrict__ s0, const float* __restrict__ s1,
                           const float* __restrict__ s2, const float* __restrict__ s3,
                           const float* __restrict__ s4,
                           bf16* __restrict__ d0, bf16* __restrict__ d1,
                           bf16* __restrict__ d2, bf16* __restrict__ d3,
                           bf16* __restrict__ d4)
{
    const int i = blockIdx.x * 256 + threadIdx.x;
    if (i < 393216) {
        const int j = i;
        const int l = (j >= 196608) ? 1 : 0;
        const int r = j - l * 196608;
        const int e     = r & 7;
        const int idx16 = r >> 3;
        const int lane  = idx16 & 63;
        const int l16   = lane & 15;
        const int quad  = lane >> 4;
        const int frag  = idx16 >> 6;        // 0..383
        const int ckk   = frag / 48;
        const int nt    = frag - ckk * 48;
        const int kc    = ckk >> 1, kk = ckk & 1;
        const int n     = nt * 16 + l16;
        const int k     = kc * 64 + (kk * 4 + quad) * 8 + e;
        d0[j] = (bf16)s0[l * 196608 + n * 256 + k];
    } else if (i < 524288) {
        const int j = i - 393216;
        const int l = j >> 16, r = j & 65535;
        const int e     = r & 7;
        const int idx16 = r >> 3;
        const int lane  = idx16 & 63;
        const int l16   = lane & 15;
        const int quad  = lane >> 4;
        const int frag  = idx16 >> 6;        // 0..127
        const int s     = frag >> 4, nt = frag & 15;
        const int n     = nt * 16 + l16;
        const int k     = s * 32 + quad * 8 + e;
        d1[j] = (bf16)s1[l * 65536 + n * 256 + k];
    } else if (i < 1048576) {
        const int j = i - 524288;
        const int l = j >> 18, r = j & 262143;
        const int e     = r & 7;
        const int idx16 = r >> 3;
        const int l16   = idx16 & 15;
        const int quad  = (idx16 >> 4) & 3;
        const int nt    = (idx16 >> 6) & 7;
        const int kk    = (idx16 >> 9) & 1;
        const int q     = (idx16 >> 10) & 3;
        const int hc    = idx16 >> 12;
        const int row   = hc * 128 + nt * 16 + l16;
        const int k     = q * 64 + (kk * 4 + quad) * 8 + e;
        d2[j] = (bf16)s2[l * 262144 + row * 256 + k];
    } else if (i < 1572864) {
        const int j = i - 1048576;
        const int l = j >> 18, r = j & 262143;
        const int e     = r & 7;
        const int idx16 = r >> 3;
        const int l16   = idx16 & 15;
        const int quad  = (idx16 >> 4) & 3;
        const int nt    = (idx16 >> 6) & 15;
        const int q     = (idx16 >> 10) & 3;
        const int hc    = idx16 >> 12;
        const int n     = nt * 16 + l16;
        const int k     = hc * 128 + q * 32 + quad * 8 + e;
        d3[j] = (bf16)s3[l * 262144 + n * 1024 + k];
    }
    else                  d4[i - 1572864] = (bf16)s4[i - 1572864];
}

// --------------------------------------------------------------------------
// feat transpose-pack: Xf[t][c] = (bf16)feat[cam][b][c][hw]
// --------------------------------------------------------------------------
__global__ __launch_bounds__(256) void feat_pack_k(const float* __restrict__ feat,
                                                   bf16* __restrict__ Xf)
{
    __shared__ float ft[64][68];

    const int tid  = threadIdx.x;
    const int camb = blockIdx.y;
    const int cam  = camb >> 1;
    const int b    = camb & 1;
    const int hw0  = blockIdx.x * 64;

    const float* fb = feat + (size_t)camb * 64 * 9216 + hw0;
#pragma unroll
    for (int rep = 0; rep < 16; ++rep) {
        const int idx = rep * 256 + tid;
        const int c = idx >> 6, p = idx & 63;
        ft[p][c] = fb[(size_t)c * 9216 + p];
    }
    __syncthreads();

    const int pbase = b * 9216 + hw0;
#pragma unroll
    for (int rep = 0; rep < 2; ++rep) {
        const int idx = rep * 256 + tid;
        const int p = idx >> 3, cc = idx & 7;
        const f32x4 a = *(const f32x4*)(&ft[p][cc * 8]);
        const f32x4 c4 = *(const f32x4*)(&ft[p][cc * 8 + 4]);
        bf16x8 v;
#pragma unroll
        for (int i = 0; i < 4; ++i) { v[i] = (bf16)a[i]; v[4 + i] = (bf16)c4[i]; }
        const size_t t = (size_t)(pbase + p) * 4 + cam;
        *(bf16x8*)(Xf + t * 64 + cc * 8) = v;
    }
}

// --------------------------------------------------------------------------
// GEMM-BT v2 (Wp projection only): 128x128 tile, counted vmcnt ping-pong.
// --------------------------------------------------------------------------
template <bool RELU>
__global__ __launch_bounds__(256, 2) void gemm_bt(
    const bf16* __restrict__ A, const bf16* __restrict__ B,
    const float* __restrict__ bias, bf16* __restrict__ C,
    int N, int K)
{
    __shared__ __align__(16) char smem[65536];

    const int tid  = threadIdx.x;
    const int lane = tid & 63;
    const int wv   = tid >> 6;
    const int wm   = wv >> 1;
    const int wn   = wv & 1;
    const int bm   = blockIdx.y * 128;
    const int bn   = blockIdx.x * 128;

    const int r8  = lane >> 3;
    const int p8  = lane & 7;
    const int gch = p8 ^ r8;

    const int quad = lane >> 4;
    const int l16  = lane & 15;

    f32x4 acc[4][4] = {};
    const int nk = K >> 6;

    auto STAGE = [&](int kc, char* base) {
#pragma unroll
        for (int inst = 0; inst < 4; ++inst) {
            const int row = wv * 32 + inst * 8 + r8;
            async_copy16(A + (size_t)(bm + row) * K + (kc * 64 + gch * 8),
                         base + (wv * 4 + inst) * 1024);
            async_copy16(B + (size_t)(bn + row) * K + (kc * 64 + gch * 8),
                         base + 16384 + (wv * 4 + inst) * 1024);
        }
    };

    STAGE(0, smem);

#pragma unroll 1
    for (int kc = 0; kc < nk; ++kc) {
        const char* cur = smem + (size_t)(kc & 1) * 32768;
        if (kc + 1 < nk) {
            STAGE(kc + 1, smem + (size_t)((kc + 1) & 1) * 32768);
            WAITV8_BAR();
        } else {
            WAITV0_BAR();
        }

#pragma unroll
        for (int kk = 0; kk < 2; ++kk) {
            bf16x8 af[4], bfr[4];
            const int lch = kk * 4 + quad;
#pragma unroll
            for (int i = 0; i < 4; ++i) {
                const int m = wm * 64 + i * 16 + l16;
                af[i] = *(const bf16x8*)(cur + (m * 8 + (lch ^ (m & 7))) * 16);
                const int n = wn * 64 + i * 16 + l16;
                bfr[i] = *(const bf16x8*)(cur + 16384 + (n * 8 + (lch ^ (n & 7))) * 16);
            }
            __builtin_amdgcn_s_setprio(1);
#pragma unroll
            for (int i = 0; i < 4; ++i)
#pragma unroll
                for (int j = 0; j < 4; ++j)
                    acc[i][j] = __builtin_amdgcn_mfma_f32_16x16x32_bf16(
                        af[i], bfr[j], acc[i][j], 0, 0, 0);
            __builtin_amdgcn_s_setprio(0);
        }
        WAITL_BAR();
    }

#pragma unroll
    for (int j = 0; j < 4; ++j) {
        const int n = bn + wn * 64 + j * 16 + l16;
        const float bv = bias[n];
#pragma unroll
        for (int i = 0; i < 4; ++i) {
            const int mb = bm + wm * 64 + i * 16 + quad * 4;
#pragma unroll
            for (int r = 0; r < 4; ++r) {
                float v = acc[i][j][r] + bv;
                if (RELU) v = fmaxf(v, 0.f);
                C[(size_t)(mb + r) * N + n] = (bf16)v;
            }
        }
    }
}

// --------------------------------------------------------------------------
// QKV GEMM v1 (R16/R18): C[73728,768] = X @ WqkvP^T + bqkv. 128x128 tile,
// grid (6,576) — column slices interleaved in dispatch keep all 6 B-slices
// L2-resident. 4 waves 1x4 (wave = 128 rows x 32 cols). B direct from
// fragment-order pack (disjoint per wave); A staged 2x16KB counted-vmcnt
// ping-pong. LDS 32KB -> 3 blocks/CU.
// --------------------------------------------------------------------------
__global__ __launch_bounds__(256, 3) void gemm_qkv_k(
    const bf16* __restrict__ A, const bf16* __restrict__ BP,
    const float* __restrict__ bias, bf16* __restrict__ C)
{
    __shared__ __align__(16) char smem[32768];

    const int tid  = threadIdx.x;
    const int lane = tid & 63;
    const int wv   = tid >> 6;
    const int wn   = wv;               // 1x4 column slice
    const int bm   = blockIdx.y * 128;
    const int bn   = blockIdx.x * 128;
    const int ntb  = blockIdx.x * 8;   // base column fragment

    const int r8  = lane >> 3;
    const int p8  = lane & 7;
    const int gch = p8 ^ r8;
    const int quad = lane >> 4;
    const int l16  = lane & 15;

    f32x4 acc[8][2] = {};

    auto STAGE = [&](int kc, char* base) {
#pragma unroll
        for (int inst = 0; inst < 4; ++inst) {
            const int row = wv * 32 + inst * 8 + r8;
            async_copy16(A + (size_t)(bm + row) * 256 + (kc * 64 + gch * 8),
                         base + (wv * 4 + inst) * 1024);
        }
    };

    STAGE(0, smem);

#pragma unroll
    for (int kc = 0; kc < 4; ++kc) {
        const char* cur = smem + (size_t)(kc & 1) * 16384;
        if (kc < 3) {
            STAGE(kc + 1, smem + (size_t)((kc + 1) & 1) * 16384);
            WAITV4_BAR();
        } else {
            WAITV0_BAR();
        }

#pragma unroll
        for (int kk = 0; kk < 2; ++kk) {
            const int lch = kk * 4 + quad;
            bf16x8 af[8], bfr[2];
#pragma unroll
            for (int j = 0; j < 2; ++j)
                bfr[j] = *(const bf16x8*)(BP +
                    ((size_t)((kc * 2 + kk) * 48 + ntb + wn * 2 + j)) * 512
                    + lane * 8);
#pragma unroll
            for (int i = 0; i < 8; ++i) {
                const int m = i * 16 + l16;
                af[i] = *(const bf16x8*)(cur + (m * 8 + (lch ^ (m & 7))) * 16);
            }
            __builtin_amdgcn_s_setprio(1);
#pragma unroll
            for (int i = 0; i < 8; ++i)
#pragma unroll
                for (int j = 0; j < 2; ++j)
                    acc[i][j] = __builtin_amdgcn_mfma_f32_16x16x32_bf16(
                        af[i], bfr[j], acc[i][j], 0, 0, 0);
            __builtin_amdgcn_s_setprio(0);
        }
        WAITL_BAR();
    }

#pragma unroll
    for (int j = 0; j < 2; ++j) {
        const int n = bn + wn * 32 + j * 16 + l16;
        const float bv = bias[n];
#pragma unroll
        for (int i = 0; i < 8; ++i) {
            const int mb = bm + i * 16 + quad * 4;
#pragma unroll
            for (int r = 0; r < 4; ++r)
                C[(size_t)(mb + r) * 768 + n] = (bf16)(acc[i][j][r] + bv);
        }
    }
}

// --------------------------------------------------------------------------
// Fused attention + Wo-GEMM + bias + residual + LayerNorm. v4 (R16/R18).
// Block = 64 rows = 16 sequences, 256 threads (4 waves), 3 blocks/CU.
// Phase 1: register attention. Phase 2: 1x4 tiling, WoP direct loads.
// LDS: SAs 32K | red[64][4] 2K = 34K.
// --------------------------------------------------------------------------
__global__ __launch_bounds__(256, 3) void attn_ln_k(
    const bf16* __restrict__ QKV, const bf16* __restrict__ WoP,
    const float* __restrict__ bias, const bf16* __restrict__ Xres,
    const float* __restrict__ gam, const float* __restrict__ bet,
    bf16* __restrict__ Xout)
{
    __shared__ __align__(16) char smem[34816];
    bf16* SAs = (bf16*)smem;                      // 64 rows x 32 chunks (32K)
    float2 (*red)[4] = (float2 (*)[4])(void*)(smem + 32768);   // [64][4]

    const int tid  = threadIdx.x;
    const int lane = tid & 63;
    const int wv   = tid >> 6;
    const int wn   = wv;               // phase-2 column slice
    const int quad = lane >> 4;
    const int l16  = lane & 15;
    const int bm   = blockIdx.x * 64;
    const int rot  = (blockIdx.x >> 3) & 7;

    // ================= phase 1: register attention, 4 seqs/wave ============
    {
        const int hh = lane >> 3;        // head 0..7
        const int cg = lane & 7;         // 4-col group 0..7
        const int s0 = blockIdx.x * 16;
        const float SCALE = 0.17677669529663687f;

#pragma unroll
        for (int g = 0; g < 4; ++g) {
            const int seq = s0 + g * 4 + wv;
            const bf16* bse = QKV + (size_t)seq * 3072 + hh * 32 + cg * 4;

            float qf[4][4], kf[4][4], vf[4][4];
#pragma unroll
            for (int i = 0; i < 4; ++i) {
                const bf16x4 qb = *(const bf16x4*)(bse + i * 768);
                const bf16x4 kb = *(const bf16x4*)(bse + i * 768 + 256);
                const bf16x4 vb = *(const bf16x4*)(bse + i * 768 + 512);
#pragma unroll
                for (int d = 0; d < 4; ++d) {
                    qf[i][d] = (float)qb[d];
                    kf[i][d] = (float)kb[d];
                    vf[i][d] = (float)vb[d];
                }
            }

            float sc[4][4];
#pragma unroll
            for (int i = 0; i < 4; ++i)
#pragma unroll
                for (int j = 0; j < 4; ++j)
                    sc[i][j] = qf[i][0] * kf[j][0] + qf[i][1] * kf[j][1]
                             + qf[i][2] * kf[j][2] + qf[i][3] * kf[j][3];

#pragma unroll
            for (int msk = 1; msk <= 4; msk <<= 1)
#pragma unroll
                for (int i = 0; i < 4; ++i)
#pragma unroll
                    for (int j = 0; j < 4; ++j)
                        sc[i][j] += __shfl_xor(sc[i][j], msk, 64);

#pragma unroll
            for (int i = 0; i < 4; ++i) {
                const float v0 = sc[i][0] * SCALE, v1 = sc[i][1] * SCALE;
                const float v2 = sc[i][2] * SCALE, v3 = sc[i][3] * SCALE;
                const float mx = fmaxf(fmaxf(v0, v1), fmaxf(v2, v3));
                const float e0 = expf(v0 - mx), e1 = expf(v1 - mx);
                const float e2 = expf(v2 - mx), e3 = expf(v3 - mx);
                const float inv = 1.f / (e0 + e1 + e2 + e3);
                sc[i][0] = e0 * inv; sc[i][1] = e1 * inv;
                sc[i][2] = e2 * inv; sc[i][3] = e3 * inv;
            }

#pragma unroll
            for (int i = 0; i < 4; ++i) {
                bf16x4 ov;
#pragma unroll
                for (int d = 0; d < 4; ++d) {
                    const float o = sc[i][0] * vf[0][d] + sc[i][1] * vf[1][d]
                                  + sc[i][2] * vf[2][d] + sc[i][3] * vf[3][d];
                    ov[d] = (bf16)o;
                }
                const int m  = (g * 4 + wv) * 4 + i;
                const int gc = lane >> 1;
                const int sl = (gc & 24) | ((gc ^ m) & 7);
                *(bf16x4*)((char*)SAs + (m * 32 + sl) * 16 + (lane & 1) * 8) = ov;
            }
        }
    }
    __syncthreads();   // SAs complete

    // ================= phase 2: Wo GEMM, 8 k-steps, direct-B, no barriers ==
    f32x4 acc[4][4] = {};

#pragma unroll
    for (int s = 0; s < 8; ++s) {
        const int sr = (s + rot) & 7;
        const int gc = sr * 4 + quad;
        bf16x8 af[4], bfr[4];
#pragma unroll
        for (int j = 0; j < 4; ++j)
            bfr[j] = *(const bf16x8*)(WoP +
                ((size_t)(sr * 16 + wn * 4 + j)) * 512 + lane * 8);
#pragma unroll
        for (int i = 0; i < 4; ++i) {
            const int m  = i * 16 + l16;
            const int sl = (gc & 24) | ((gc ^ m) & 7);
            af[i] = *(const bf16x8*)((const char*)SAs + (m * 32 + sl) * 16);
        }
        __builtin_amdgcn_s_setprio(1);
#pragma unroll
        for (int i = 0; i < 4; ++i)
#pragma unroll
            for (int j = 0; j < 4; ++j)
                acc[i][j] = __builtin_amdgcn_mfma_f32_16x16x32_bf16(
                    af[i], bfr[j], acc[i][j], 0, 0, 0);
        __builtin_amdgcn_s_setprio(0);
    }

    // ---- epilogue: bias + residual (global) + LayerNorm; red[64][4]
    float bv[4], gv[4], bev[4];
#pragma unroll
    for (int j = 0; j < 4; ++j) {
        const int n = wn * 64 + j * 16 + l16;
        bv[j] = bias[n]; gv[j] = gam[n]; bev[j] = bet[n];
    }

#pragma unroll
    for (int i = 0; i < 4; ++i) {
#pragma unroll
        for (int r = 0; r < 4; ++r) {
            const int rl = i * 16 + quad * 4 + r;
            const size_t row = (size_t)(bm + rl);
            float s1 = 0.f, s2 = 0.f;
#pragma unroll
            for (int j = 0; j < 4; ++j) {
                const int n = wn * 64 + j * 16 + l16;
                const float v = acc[i][j][r] + bv[j] + (float)Xres[row * 256 + n];
                acc[i][j][r] = v;
                s1 += v; s2 += v * v;
            }
#pragma unroll
            for (int off = 1; off < 16; off <<= 1) {
                s1 += __shfl_xor(s1, off, 64);
                s2 += __shfl_xor(s2, off, 64);
            }
            if (l16 == 0) red[rl][wn] = make_float2(s1, s2);
        }
    }
    __syncthreads();

#pragma unroll
    for (int i = 0; i < 4; ++i) {
#pragma unroll
        for (int r = 0; r < 4; ++r) {
            const int rl = i * 16 + quad * 4 + r;
            const float2 p0 = red[rl][0], p1 = red[rl][1];
            const float2 p2 = red[rl][2], p3 = red[rl][3];
            const float mu  = (p0.x + p1.x + p2.x + p3.x) * (1.f / 256.f);
            const float ex2 = (p0.y + p1.y + p2.y + p3.y) * (1.f / 256.f);
            const float rstd = rsqrtf(fmaxf(ex2 - mu * mu, 0.f) + 1e-5f);
            const size_t row = (size_t)(bm + rl);
#pragma unroll
            for (int j = 0; j < 4; ++j) {
                const int n = wn * 64 + j * 16 + l16;
                Xout[row * 256 + n] = (bf16)((acc[i][j][r] - mu) * rstd * gv[j] + bev[j]);
            }
        }
    }
}

// --------------------------------------------------------------------------
// Fused FFN v9 (R15 exact): 64-row tile, grid 1152, 4 waves 1x4,
// 3 blocks/CU. W1P/W2P fragment-order direct, disjoint per wave.
// hc rotated by bits 3-5 of blockIdx. 2 lgkm-only barriers per hc.
// LDS: Xs 32K | Ts 16K (red[64][4] aliases) = 48KB.
// --------------------------------------------------------------------------
__global__ __launch_bounds__(256, 3) void ffn_fused_k(
    const bf16* __restrict__ X,
    const bf16* __restrict__ W1P, const float* __restrict__ b1,
    const bf16* __restrict__ W2P, const float* __restrict__ b2,
    const float* __restrict__ gam, const float* __restrict__ bet,
    bf16* __restrict__ Xout)
{
    __shared__ __align__(16) char smem[49152];
    bf16* Xs = (bf16*)smem;                       // 64 x 256 (32 slots/row)
    bf16* Ts = (bf16*)(smem + 32768);             // 64 x 128 (16 slots/row)
    float2 (*red)[4] = (float2 (*)[4])(void*)(smem + 32768);   // aliases Ts

    const int tid  = threadIdx.x;
    const int lane = tid & 63;
    const int wn   = tid >> 6;          // 0..3: wave's column slice
    const int quad = lane >> 4;
    const int l16  = lane & 15;
    const int bm   = blockIdx.x * 64;
    const int rot  = (blockIdx.x >> 3) & 7;

    // prologue: stage Xs once (the only global_load_lds traffic)
#pragma unroll
    for (int it = 0; it < 8; ++it) {
        const int L = it * 256 + tid;
        const int row = L >> 5, slot = L & 31;
        const int gch = (slot & 24) | ((slot ^ row) & 7);
        async_copy16(X + (size_t)(bm + row) * 256 + gch * 8,
                     (char*)Xs + (size_t)L * 16);
    }
    WAITV0_BAR();

    f32x4 acc2[4][4] = {};

#pragma unroll 1
    for (int hc = 0; hc < 8; ++hc) {
        const int hcr = (hc + rot) & 7;
        float b1v[2];
#pragma unroll
        for (int j = 0; j < 2; ++j)
            b1v[j] = b1[hcr * 128 + wn * 32 + j * 16 + l16];

        f32x4 accA[4][2] = {};

        // ---- phase A: accA = Xs @ W1c^T (wave cols wn*32..+31). No barriers.
#pragma unroll
        for (int q = 0; q < 4; ++q) {
#pragma unroll
            for (int kk = 0; kk < 2; ++kk) {
                const int ch = kk * 4 + quad;
                const int gc = q * 8 + ch;
                bf16x8 af[4], bfr[2];
#pragma unroll
                for (int j = 0; j < 2; ++j)
                    bfr[j] = *(const bf16x8*)(W1P +
                        ((size_t)(((hcr * 4 + q) * 2 + kk) * 8) + wn * 2 + j) * 512
                        + lane * 8);
#pragma unroll
                for (int i = 0; i < 4; ++i) {
                    const int m  = i * 16 + l16;
                    const int sl = (gc & 24) | ((gc ^ m) & 7);
                    af[i] = *(const bf16x8*)((const char*)Xs + (m * 32 + sl) * 16);
                }
                __builtin_amdgcn_s_setprio(1);
#pragma unroll
                for (int i = 0; i < 4; ++i)
#pragma unroll
                    for (int j = 0; j < 2; ++j)
                        accA[i][j] = __builtin_amdgcn_mfma_f32_16x16x32_bf16(
                            af[i], bfr[j], accA[i][j], 0, 0, 0);
                __builtin_amdgcn_s_setprio(0);
            }
        }

        // ---- Ts = relu(accA + b1)  (wave writes cols wn*32..+31)
#pragma unroll
        for (int j = 0; j < 2; ++j) {
            const int h  = wn * 32 + j * 16 + l16;
            const float bb = b1v[j];
            const int g  = h >> 3;
#pragma unroll
            for (int i = 0; i < 4; ++i)
#pragma unroll
                for (int r = 0; r < 4; ++r) {
                    const int m  = i * 16 + quad * 4 + r;
                    const int sl = (g & 8) | ((g ^ m) & 7);
                    const float v = fmaxf(accA[i][j][r] + bb, 0.f);
                    *((bf16*)((char*)Ts + (m * 16 + sl) * 16 + (h & 7) * 2)) = (bf16)v;
                }
        }
        WAITL_BAR();      // Ts writes visible (lgkm only — no vmem drain)

        // ---- phase B: acc2 += Ts @ W2c^T (wave cols wn*64..+63). W2P direct.
#pragma unroll
        for (int q = 0; q < 4; ++q) {
            const int tc = q * 4 + quad;
            bf16x8 af[4], bfr[4];
#pragma unroll
            for (int j = 0; j < 4; ++j)
                bfr[j] = *(const bf16x8*)(W2P +
                    ((size_t)((hcr * 4 + q) * 16) + wn * 4 + j) * 512
                    + lane * 8);
#pragma unroll
            for (int i = 0; i < 4; ++i) {
                const int m  = i * 16 + l16;
                const int sl = (tc & 8) | ((tc ^ m) & 7);
                af[i] = *(const bf16x8*)((const char*)Ts + (m * 16 + sl) * 16);
            }
            __builtin_amdgcn_s_setprio(1);
#pragma unroll
            for (int i = 0; i < 4; ++i)
#pragma unroll
                for (int j = 0; j < 4; ++j)
                    acc2[i][j] = __builtin_amdgcn_mfma_f32_16x16x32_bf16(
                        af[i], bfr[j], acc2[i][j], 0, 0, 0);
            __builtin_amdgcn_s_setprio(0);
        }
        WAITL_BAR();      // phase-B Ts reads done before next hc overwrites
    }

    // ---- epilogue: bias + residual (from Xs) + LayerNorm
    float bv[4], gv[4], bev[4];
#pragma unroll
    for (int j = 0; j < 4; ++j) {
        const int n = wn * 64 + j * 16 + l16;
        bv[j] = b2[n]; gv[j] = gam[n]; bev[j] = bet[n];
    }

#pragma unroll
    for (int i = 0; i < 4; ++i) {
#pragma unroll
        for (int r = 0; r < 4; ++r) {
            const int rl = i * 16 + quad * 4 + r;
            float s1 = 0.f, s2 = 0.f;
#pragma unroll
            for (int j = 0; j < 4; ++j) {
                const int n  = wn * 64 + j * 16 + l16;
                const int gc = n >> 3;
                const int sl = (gc & 24) | ((gc ^ rl) & 7);
                const float xr = (float)*((const bf16*)((const char*)Xs +
                                   (rl * 32 + sl) * 16 + (n & 7) * 2));
                const float v = acc2[i][j][r] + bv[j] + xr;
                acc2[i][j][r] = v;
                s1 += v; s2 += v * v;
            }
#pragma unroll
            for (int off = 1; off < 16; off <<= 1) {
                s1 += __shfl_xor(s1, off, 64);
                s2 += __shfl_xor(s2, off, 64);
            }
            if (l16 == 0) red[rl][wn] = make_float2(s1, s2);
        }
    }
    __syncthreads();

#pragma unroll
    for (int i = 0; i < 4; ++i) {
#pragma unroll
        for (int r = 0; r < 4; ++r) {
            const int rl = i * 16 + quad * 4 + r;
            const float2 p0 = red[rl][0], p1 = red[rl][1];
            const float2 p2 = red[rl][2], p3 = red[rl][3];
            const float mu  = (p0.x + p1.x + p2.x + p3.x) * (1.f / 256.f);
            const float ex2 = (p0.y + p1.y + p2.y + p3.y) * (1.f / 256.f);
            const float rstd = rsqrtf(fmaxf(ex2 - mu * mu, 0.f) + 1e-5f);
            const size_t row = (size_t)(bm + rl);
#pragma unroll
            for (int j = 0; j < 4; ++j) {
                const int n = wn * 64 + j * 16 + l16;
                Xout[row * 256 + n] = (bf16)((acc2[i][j][r] - mu) * rstd * gv[j] + bev[j]);
            }
        }
    }
}

// --------------------------------------------------------------------------
// out[b][c][hw] = sum_e (mean_cam X[p*4+cam][e]) * Wout[c][e] + bout[c]
// --------------------------------------------------------------------------
__global__ __launch_bounds__(256) void out_proj_k(const bf16* __restrict__ X,
                                                  const float* __restrict__ Wout,
                                                  const float* __restrict__ bout,
                                                  float* __restrict__ out)
{
    __shared__ float fused[16][260];
    const int tid = threadIdx.x;
    const int p0  = blockIdx.x * 16;

#pragma unroll
    for (int it = 0; it < 16; ++it) {
        const int idx = it * 256 + tid;
        const int pix = idx >> 8, e = idx & 255;
        const size_t base = (size_t)(p0 + pix) * 1024 + e;
        const float s = (float)X[base] + (float)X[base + 256] +
                        (float)X[base + 512] + (float)X[base + 768];
        fused[pix][e] = s * 0.25f;
    }
    __syncthreads();

    const int pix = tid & 15;
    const int c0  = tid >> 4;
    const int p   = p0 + pix;
    const int b   = p / 9216;
    const int hw  = p % 9216;
#pragma unroll
    for (int it = 0; it < 4; ++it) {
        const int c = it * 16 + c0;
        const float* w = Wout + c * 256;
        float acc = bout[c];
#pragma unroll 8
        for (int e = 0; e < 256; ++e) acc += fused[pix][e] * w[e];
        out[((size_t)b * 64 + c) * 9216 + hw] = acc;
    }
}

// --------------------------------------------------------------------------
extern "C" void kernel_launch(void* const* d_in, const int* in_sizes, int n_in,
                              void* d_out, int out_size, void* d_ws, size_t ws_size,
                              hipStream_t stream)
{
    const float* features = (const float*)d_in[0];
    const float* Wp   = (const float*)d_in[1];
    const float* bp   = (const float*)d_in[2];
    const float* Wqkv = (const float*)d_in[3];
    const float* bqkv = (const float*)d_in[4];
    const float* Wo   = (const float*)d_in[5];
    const float* bo   = (const float*)d_in[6];
    const float* W1   = (const float*)d_in[7];
    const float* b1   = (const float*)d_in[8];
    const float* W2   = (const float*)d_in[9];
    const float* b2   = (const float*)d_in[10];
    const float* g1   = (const float*)d_in[11];
    const float* be1  = (const float*)d_in[12];
    const float* g2   = (const float*)d_in[13];
    const float* be2  = (const float*)d_in[14];
    const float* Wout = (const float*)d_in[15];
    const float* bout = (const float*)d_in[16];
    float* out = (float*)d_out;

    char* ws = (char*)d_ws;
    bf16* X   = (bf16*)(ws);                    // 73728*256
    bf16* QKV = (bf16*)(ws + 37748736ull);      // 73728*768
    bf16* Xf  = (bf16*)(ws + 188743680ull);     // 73728*64
    bf16* WpB = (bf16*)(ws + 198180864ull);     // 256*64
    bf16* Wb  = (bf16*)(ws + 226492416ull);     // packed bf16 weights

    bf16* WqkvB = Wb;                  // 2 x 768*256 (fragment order)
    bf16* WoB   = Wb + 393216;         // 2 x 256*256 (fragment order)
    bf16* W1B   = Wb + 524288;         // 2 x 1024*256 (fragment order)
    bf16* W2B   = Wb + 1048576;        // 2 x 256*1024 (fragment order)

    pack_all_k<<<6208, 256, 0, stream>>>(Wqkv, Wo, W1, W2, Wp,
                                         WqkvB, WoB, W1B, W2B, WpB);

    feat_pack_k<<<dim3(144, 8), 256, 0, stream>>>(features, Xf);
    gemm_bt<false><<<dim3(2, 576), 256, 0, stream>>>(Xf, WpB, bp, X, 256, 64);

    for (int l = 0; l < 2; ++l) {
        gemm_qkv_k<<<dim3(6, 576), 256, 0, stream>>>(
            X, WqkvB + l * 196608, bqkv + l * 768, QKV);
        attn_ln_k<<<1152, 256, 0, stream>>>(
            QKV, WoB + l * 65536, bo + l * 256, X,
            g1 + l * 256, be1 + l * 256, X);
        ffn_fused_k<<<1152, 256, 0, stream>>>(
            X, W1B + l * 262144, b1 + l * 1024,
            W2B + l * 262144, b2 + l * 256,
            g2 + l * 256, be2 + l * 256, X);
    }

    out_proj_k<<<1152, 256, 0, stream>>>(X, Wout, bout, out);
}

// Round 14
// 569.144 us; speedup vs baseline: 1.2773x; 1.0055x over previous
//
#include <hip/hip_runtime.h>
#include <cstdint>
#include <cstddef>

// ---------------------------------------------------------------------------
// TransformerMultiViewFusion (MI355X / gfx950), round 21.
//
//  R21 change: gemm_qkv_k grid (6,576) -> (3,576). The 128-row A-tile was
//  staged through the ~16B/cyc/CU gload_lds port SIX times (226 MB/layer for
//  a 37.7MB matrix). Now 3x (113 MB): each block computes 256 columns,
//  wave = 128 rows x 64 cols (4 B-frags, acc[8][4], ~200 VGPR -> 2 blk/CU).
//  B L2 traffic unchanged (1728 x 131KB = same 226 MB); per-block weight
//  working set 131KB stays L2-co-resident (no R17 thrash signature).
//  Everything else locked at R18 (570-572us verified).
//
//  Design rules learned (R7-R20):
//   - gload_lds staging port ~16 B/cyc/CU; direct fragment-order vmem ~29.
//   - direct loads must be DISJOINT per wave (1x4 tiling).
//   - per-block weight working set must stay L2-co-resident; keep column
//     slices interleaved across the dispatch.
//   - hc rotation helps; scattering a sequential fragment stream hurts.
//   - no explicit cross-barrier prefetch registers: compiler spills them.
//
//  Workspace: X@0 | QKV@37748736 | Xf@188743680 | WpB@198180864 |
//             Wb@226492416
// ---------------------------------------------------------------------------

typedef __bf16 bf16;
typedef __bf16 bf16x8 __attribute__((ext_vector_type(8)));
typedef __bf16 bf16x4 __attribute__((ext_vector_type(4)));
typedef float  f32x4  __attribute__((ext_vector_type(4)));

__device__ __forceinline__ void async_copy16(const void* g, void* l)
{
    __builtin_amdgcn_global_load_lds(
        (__attribute__((address_space(1))) void*)g,
        (__attribute__((address_space(3))) void*)l,
        16, 0, 0);
}

#define WAITV8_BAR() asm volatile("s_waitcnt vmcnt(8)\ns_barrier" ::: "memory")
#define WAITV4_BAR() asm volatile("s_waitcnt vmcnt(4)\ns_barrier" ::: "memory")
#define WAITV0_BAR() asm volatile("s_waitcnt vmcnt(0)\ns_barrier" ::: "memory")
#define WAITL_BAR()  asm volatile("s_waitcnt lgkmcnt(0)\ns_barrier" ::: "memory")

// --------------------------------------------------------------------------
// all 5 weight packs in one launch. 1589248 = 6208*256 exactly.
// Wqkv -> fragment order: frag = (kc*2+kk)*48 + nt (nt 0..47).
// Wo   -> fragment order: frag = s*16 + nt (s 0..7, nt 0..15).
// W1   -> fragment order: frag = ((hc*4+q)*2+kk)*8 + nt.
// W2   -> fragment order: frag = (hc*4+q)*16 + nt.
// --------------------------------------------------------------------------
__global__ void pack_all_k(const float* __restrict__ s0, const float* __restrict__ s1,
                           const float* __restrict__ s2, const float* __restrict__ s3,
                           const float* __restrict__ s4,
                           bf16* __restrict__ d0, bf16* __restrict__ d1,
                           bf16* __restrict__ d2, bf16* __restrict__ d3,
                           bf16* __restrict__ d4)
{
    const int i = blockIdx.x * 256 + threadIdx.x;
    if (i < 393216) {
        const int j = i;
        const int l = (j >= 196608) ? 1 : 0;
        const int r = j - l * 196608;
        const int e     = r & 7;
        const int idx16 = r >> 3;
        const int lane  = idx16 & 63;
        const int l16   = lane & 15;
        const int quad  = lane >> 4;
        const int frag  = idx16 >> 6;        // 0..383
        const int ckk   = frag / 48;
        const int nt    = frag - ckk * 48;
        const int kc    = ckk >> 1, kk = ckk & 1;
        const int n     = nt * 16 + l16;
        const int k     = kc * 64 + (kk * 4 + quad) * 8 + e;
        d0[j] = (bf16)s0[l * 196608 + n * 256 + k];
    } else if (i < 524288) {
        const int j = i - 393216;
        const int l = j >> 16, r = j & 65535;
        const int e     = r & 7;
        const int idx16 = r >> 3;
        const int lane  = idx16 & 63;
        const int l16   = lane & 15;
        const int quad  = lane >> 4;
        const int frag  = idx16 >> 6;        // 0..127
        const int s     = frag >> 4, nt = frag & 15;
        const int n     = nt * 16 + l16;
        const int k     = s * 32 + quad * 8 + e;
        d1[j] = (bf16)s1[l * 65536 + n * 256 + k];
    } else if (i < 1048576) {
        const int j = i - 524288;
        const int l = j >> 18, r = j & 262143;
        const int e     = r & 7;
        const int idx16 = r >> 3;
        const int l16   = idx16 & 15;
        const int quad  = (idx16 >> 4) & 3;
        const int nt    = (idx16 >> 6) & 7;
        const int kk    = (idx16 >> 9) & 1;
        const int q     = (idx16 >> 10) & 3;
        const int hc    = idx16 >> 12;
        const int row   = hc * 128 + nt * 16 + l16;
        const int k     = q * 64 + (kk * 4 + quad) * 8 + e;
        d2[j] = (bf16)s2[l * 262144 + row * 256 + k];
    } else if (i < 1572864) {
        const int j = i - 1048576;
        const int l = j >> 18, r = j & 262143;
        const int e     = r & 7;
        const int idx16 = r >> 3;
        const int l16   = idx16 & 15;
        const int quad  = (idx16 >> 4) & 3;
        const int nt    = (idx16 >> 6) & 15;
        const int q     = (idx16 >> 10) & 3;
        const int hc    = idx16 >> 12;
        const int n     = nt * 16 + l16;
        const int k     = hc * 128 + q * 32 + quad * 8 + e;
        d3[j] = (bf16)s3[l * 262144 + n * 1024 + k];
    }
    else                  d4[i - 1572864] = (bf16)s4[i - 1572864];
}

// --------------------------------------------------------------------------
// feat transpose-pack: Xf[t][c] = (bf16)feat[cam][b][c][hw]
// --------------------------------------------------------------------------
__global__ __launch_bounds__(256) void feat_pack_k(const float* __restrict__ feat,
                                                   bf16* __restrict__ Xf)
{
    __shared__ float ft[64][68];

    const int tid  = threadIdx.x;
    const int camb = blockIdx.y;
    const int cam  = camb >> 1;
    const int b    = camb & 1;
    const int hw0  = blockIdx.x * 64;

    const float* fb = feat + (size_t)camb * 64 * 9216 + hw0;
#pragma unroll
    for (int rep = 0; rep < 16; ++rep) {
        const int idx = rep * 256 + tid;
        const int c = idx >> 6, p = idx & 63;
        ft[p][c] = fb[(size_t)c * 9216 + p];
    }
    __syncthreads();

    const int pbase = b * 9216 + hw0;
#pragma unroll
    for (int rep = 0; rep < 2; ++rep) {
        const int idx = rep * 256 + tid;
        const int p = idx >> 3, cc = idx & 7;
        const f32x4 a = *(const f32x4*)(&ft[p][cc * 8]);
        const f32x4 c4 = *(const f32x4*)(&ft[p][cc * 8 + 4]);
        bf16x8 v;
#pragma unroll
        for (int i = 0; i < 4; ++i) { v[i] = (bf16)a[i]; v[4 + i] = (bf16)c4[i]; }
        const size_t t = (size_t)(pbase + p) * 4 + cam;
        *(bf16x8*)(Xf + t * 64 + cc * 8) = v;
    }
}

// --------------------------------------------------------------------------
// GEMM-BT v2 (Wp projection only): 128x128 tile, counted vmcnt ping-pong.
// --------------------------------------------------------------------------
template <bool RELU>
__global__ __launch_bounds__(256, 2) void gemm_bt(
    const bf16* __restrict__ A, const bf16* __restrict__ B,
    const float* __restrict__ bias, bf16* __restrict__ C,
    int N, int K)
{
    __shared__ __align__(16) char smem[65536];

    const int tid  = threadIdx.x;
    const int lane = tid & 63;
    const int wv   = tid >> 6;
    const int wm   = wv >> 1;
    const int wn   = wv & 1;
    const int bm   = blockIdx.y * 128;
    const int bn   = blockIdx.x * 128;

    const int r8  = lane >> 3;
    const int p8  = lane & 7;
    const int gch = p8 ^ r8;

    const int quad = lane >> 4;
    const int l16  = lane & 15;

    f32x4 acc[4][4] = {};
    const int nk = K >> 6;

    auto STAGE = [&](int kc, char* base) {
#pragma unroll
        for (int inst = 0; inst < 4; ++inst) {
            const int row = wv * 32 + inst * 8 + r8;
            async_copy16(A + (size_t)(bm + row) * K + (kc * 64 + gch * 8),
                         base + (wv * 4 + inst) * 1024);
            async_copy16(B + (size_t)(bn + row) * K + (kc * 64 + gch * 8),
                         base + 16384 + (wv * 4 + inst) * 1024);
        }
    };

    STAGE(0, smem);

#pragma unroll 1
    for (int kc = 0; kc < nk; ++kc) {
        const char* cur = smem + (size_t)(kc & 1) * 32768;
        if (kc + 1 < nk) {
            STAGE(kc + 1, smem + (size_t)((kc + 1) & 1) * 32768);
            WAITV8_BAR();
        } else {
            WAITV0_BAR();
        }

#pragma unroll
        for (int kk = 0; kk < 2; ++kk) {
            bf16x8 af[4], bfr[4];
            const int lch = kk * 4 + quad;
#pragma unroll
            for (int i = 0; i < 4; ++i) {
                const int m = wm * 64 + i * 16 + l16;
                af[i] = *(const bf16x8*)(cur + (m * 8 + (lch ^ (m & 7))) * 16);
                const int n = wn * 64 + i * 16 + l16;
                bfr[i] = *(const bf16x8*)(cur + 16384 + (n * 8 + (lch ^ (n & 7))) * 16);
            }
            __builtin_amdgcn_s_setprio(1);
#pragma unroll
            for (int i = 0; i < 4; ++i)
#pragma unroll
                for (int j = 0; j < 4; ++j)
                    acc[i][j] = __builtin_amdgcn_mfma_f32_16x16x32_bf16(
                        af[i], bfr[j], acc[i][j], 0, 0, 0);
            __builtin_amdgcn_s_setprio(0);
        }
        WAITL_BAR();
    }

#pragma unroll
    for (int j = 0; j < 4; ++j) {
        const int n = bn + wn * 64 + j * 16 + l16;
        const float bv = bias[n];
#pragma unroll
        for (int i = 0; i < 4; ++i) {
            const int mb = bm + wm * 64 + i * 16 + quad * 4;
#pragma unroll
            for (int r = 0; r < 4; ++r) {
                float v = acc[i][j][r] + bv;
                if (RELU) v = fmaxf(v, 0.f);
                C[(size_t)(mb + r) * N + n] = (bf16)v;
            }
        }
    }
}

// --------------------------------------------------------------------------
// QKV GEMM v3: C[73728,768] = X @ WqkvP^T + bqkv. Grid (3,576): 128 rows x
// 256 cols per block -> A staged only 3x (113 MB/layer vs 226 at (6,576)).
// 4 waves 1x4 (wave = 128 rows x 64 cols, 4 B-frags, acc[8][4]). B direct
// from fragment-order pack (disjoint per wave); A staged 2x16KB counted-
// vmcnt ping-pong. LDS 32KB; ~200 VGPR -> 2 blocks/CU.
// --------------------------------------------------------------------------
__global__ __launch_bounds__(256, 2) void gemm_qkv_k(
    const bf16* __restrict__ A, const bf16* __restrict__ BP,
    const float* __restrict__ bias, bf16* __restrict__ C)
{
    __shared__ __align__(16) char smem[32768];

    const int tid  = threadIdx.x;
    const int lane = tid & 63;
    const int wv   = tid >> 6;
    const int wn   = wv;               // 1x4 column slice (64 cols each)
    const int bm   = blockIdx.y * 128;
    const int bn   = blockIdx.x * 256;
    const int ntb  = blockIdx.x * 16;  // base column fragment (of 48)

    const int r8  = lane >> 3;
    const int p8  = lane & 7;
    const int gch = p8 ^ r8;
    const int quad = lane >> 4;
    const int l16  = lane & 15;

    f32x4 acc[8][4] = {};

    auto STAGE = [&](int kc, char* base) {
#pragma unroll
        for (int inst = 0; inst < 4; ++inst) {
            const int row = wv * 32 + inst * 8 + r8;
            async_copy16(A + (size_t)(bm + row) * 256 + (kc * 64 + gch * 8),
                         base + (wv * 4 + inst) * 1024);
        }
    };

    STAGE(0, smem);

#pragma unroll
    for (int kc = 0; kc < 4; ++kc) {
        const char* cur = smem + (size_t)(kc & 1) * 16384;
        if (kc < 3) {
            STAGE(kc + 1, smem + (size_t)((kc + 1) & 1) * 16384);
            WAITV4_BAR();
        } else {
            WAITV0_BAR();
        }

#pragma unroll
        for (int kk = 0; kk < 2; ++kk) {
            const int lch = kk * 4 + quad;
            bf16x8 af[8], bfr[4];
#pragma unroll
            for (int j = 0; j < 4; ++j)
                bfr[j] = *(const bf16x8*)(BP +
                    ((size_t)((kc * 2 + kk) * 48 + ntb + wn * 4 + j)) * 512
                    + lane * 8);
#pragma unroll
            for (int i = 0; i < 8; ++i) {
                const int m = i * 16 + l16;
                af[i] = *(const bf16x8*)(cur + (m * 8 + (lch ^ (m & 7))) * 16);
            }
            __builtin_amdgcn_s_setprio(1);
#pragma unroll
            for (int i = 0; i < 8; ++i)
#pragma unroll
                for (int j = 0; j < 4; ++j)
                    acc[i][j] = __builtin_amdgcn_mfma_f32_16x16x32_bf16(
                        af[i], bfr[j], acc[i][j], 0, 0, 0);
            __builtin_amdgcn_s_setprio(0);
        }
        WAITL_BAR();
    }

#pragma unroll
    for (int j = 0; j < 4; ++j) {
        const int n = bn + wn * 64 + j * 16 + l16;
        const float bv = bias[n];
#pragma unroll
        for (int i = 0; i < 8; ++i) {
            const int mb = bm + i * 16 + quad * 4;
#pragma unroll
            for (int r = 0; r < 4; ++r)
                C[(size_t)(mb + r) * 768 + n] = (bf16)(acc[i][j][r] + bv);
        }
    }
}

// --------------------------------------------------------------------------
// Fused attention + Wo-GEMM + bias + residual + LayerNorm. v4 (R16/R18).
// Block = 64 rows = 16 sequences, 256 threads (4 waves), 3 blocks/CU.
// Phase 1: register attention. Phase 2: 1x4 tiling, WoP direct loads.
// LDS: SAs 32K | red[64][4] 2K = 34K.
// --------------------------------------------------------------------------
__global__ __launch_bounds__(256, 3) void attn_ln_k(
    const bf16* __restrict__ QKV, const bf16* __restrict__ WoP,
    const float* __restrict__ bias, const bf16* __restrict__ Xres,
    const float* __restrict__ gam, const float* __restrict__ bet,
    bf16* __restrict__ Xout)
{
    __shared__ __align__(16) char smem[34816];
    bf16* SAs = (bf16*)smem;                      // 64 rows x 32 chunks (32K)
    float2 (*red)[4] = (float2 (*)[4])(void*)(smem + 32768);   // [64][4]

    const int tid  = threadIdx.x;
    const int lane = tid & 63;
    const int wv   = tid >> 6;
    const int wn   = wv;               // phase-2 column slice
    const int quad = lane >> 4;
    const int l16  = lane & 15;
    const int bm   = blockIdx.x * 64;
    const int rot  = (blockIdx.x >> 3) & 7;

    // ================= phase 1: register attention, 4 seqs/wave ============
    {
        const int hh = lane >> 3;        // head 0..7
        const int cg = lane & 7;         // 4-col group 0..7
        const int s0 = blockIdx.x * 16;
        const float SCALE = 0.17677669529663687f;

#pragma unroll
        for (int g = 0; g < 4; ++g) {
            const int seq = s0 + g * 4 + wv;
            const bf16* bse = QKV + (size_t)seq * 3072 + hh * 32 + cg * 4;

            float qf[4][4], kf[4][4], vf[4][4];
#pragma unroll
            for (int i = 0; i < 4; ++i) {
                const bf16x4 qb = *(const bf16x4*)(bse + i * 768);
                const bf16x4 kb = *(const bf16x4*)(bse + i * 768 + 256);
                const bf16x4 vb = *(const bf16x4*)(bse + i * 768 + 512);
#pragma unroll
                for (int d = 0; d < 4; ++d) {
                    qf[i][d] = (float)qb[d];
                    kf[i][d] = (float)kb[d];
                    vf[i][d] = (float)vb[d];
                }
            }

            float sc[4][4];
#pragma unroll
            for (int i = 0; i < 4; ++i)
#pragma unroll
                for (int j = 0; j < 4; ++j)
                    sc[i][j] = qf[i][0] * kf[j][0] + qf[i][1] * kf[j][1]
                             + qf[i][2] * kf[j][2] + qf[i][3] * kf[j][3];

#pragma unroll
            for (int msk = 1; msk <= 4; msk <<= 1)
#pragma unroll
                for (int i = 0; i < 4; ++i)
#pragma unroll
                    for (int j = 0; j < 4; ++j)
                        sc[i][j] += __shfl_xor(sc[i][j], msk, 64);

#pragma unroll
            for (int i = 0; i < 4; ++i) {
                const float v0 = sc[i][0] * SCALE, v1 = sc[i][1] * SCALE;
                const float v2 = sc[i][2] * SCALE, v3 = sc[i][3] * SCALE;
                const float mx = fmaxf(fmaxf(v0, v1), fmaxf(v2, v3));
                const float e0 = expf(v0 - mx), e1 = expf(v1 - mx);
                const float e2 = expf(v2 - mx), e3 = expf(v3 - mx);
                const float inv = 1.f / (e0 + e1 + e2 + e3);
                sc[i][0] = e0 * inv; sc[i][1] = e1 * inv;
                sc[i][2] = e2 * inv; sc[i][3] = e3 * inv;
            }

#pragma unroll
            for (int i = 0; i < 4; ++i) {
                bf16x4 ov;
#pragma unroll
                for (int d = 0; d < 4; ++d) {
                    const float o = sc[i][0] * vf[0][d] + sc[i][1] * vf[1][d]
                                  + sc[i][2] * vf[2][d] + sc[i][3] * vf[3][d];
                    ov[d] = (bf16)o;
                }
                const int m  = (g * 4 + wv) * 4 + i;
                const int gc = lane >> 1;
                const int sl = (gc & 24) | ((gc ^ m) & 7);
                *(bf16x4*)((char*)SAs + (m * 32 + sl) * 16 + (lane & 1) * 8) = ov;
            }
        }
    }
    __syncthreads();   // SAs complete

    // ================= phase 2: Wo GEMM, 8 k-steps, direct-B, no barriers ==
    f32x4 acc[4][4] = {};

#pragma unroll
    for (int s = 0; s < 8; ++s) {
        const int sr = (s + rot) & 7;
        const int gc = sr * 4 + quad;
        bf16x8 af[4], bfr[4];
#pragma unroll
        for (int j = 0; j < 4; ++j)
            bfr[j] = *(const bf16x8*)(WoP +
                ((size_t)(sr * 16 + wn * 4 + j)) * 512 + lane * 8);
#pragma unroll
        for (int i = 0; i < 4; ++i) {
            const int m  = i * 16 + l16;
            const int sl = (gc & 24) | ((gc ^ m) & 7);
            af[i] = *(const bf16x8*)((const char*)SAs + (m * 32 + sl) * 16);
        }
        __builtin_amdgcn_s_setprio(1);
#pragma unroll
        for (int i = 0; i < 4; ++i)
#pragma unroll
            for (int j = 0; j < 4; ++j)
                acc[i][j] = __builtin_amdgcn_mfma_f32_16x16x32_bf16(
                    af[i], bfr[j], acc[i][j], 0, 0, 0);
        __builtin_amdgcn_s_setprio(0);
    }

    // ---- epilogue: bias + residual (global) + LayerNorm; red[64][4]
    float bv[4], gv[4], bev[4];
#pragma unroll
    for (int j = 0; j < 4; ++j) {
        const int n = wn * 64 + j * 16 + l16;
        bv[j] = bias[n]; gv[j] = gam[n]; bev[j] = bet[n];
    }

#pragma unroll
    for (int i = 0; i < 4; ++i) {
#pragma unroll
        for (int r = 0; r < 4; ++r) {
            const int rl = i * 16 + quad * 4 + r;
            const size_t row = (size_t)(bm + rl);
            float s1 = 0.f, s2 = 0.f;
#pragma unroll
            for (int j = 0; j < 4; ++j) {
                const int n = wn * 64 + j * 16 + l16;
                const float v = acc[i][j][r] + bv[j] + (float)Xres[row * 256 + n];
                acc[i][j][r] = v;
                s1 += v; s2 += v * v;
            }
#pragma unroll
            for (int off = 1; off < 16; off <<= 1) {
                s1 += __shfl_xor(s1, off, 64);
                s2 += __shfl_xor(s2, off, 64);
            }
            if (l16 == 0) red[rl][wn] = make_float2(s1, s2);
        }
    }
    __syncthreads();

#pragma unroll
    for (int i = 0; i < 4; ++i) {
#pragma unroll
        for (int r = 0; r < 4; ++r) {
            const int rl = i * 16 + quad * 4 + r;
            const float2 p0 = red[rl][0], p1 = red[rl][1];
            const float2 p2 = red[rl][2], p3 = red[rl][3];
            const float mu  = (p0.x + p1.x + p2.x + p3.x) * (1.f / 256.f);
            const float ex2 = (p0.y + p1.y + p2.y + p3.y) * (1.f / 256.f);
            const float rstd = rsqrtf(fmaxf(ex2 - mu * mu, 0.f) + 1e-5f);
            const size_t row = (size_t)(bm + rl);
#pragma unroll
            for (int j = 0; j < 4; ++j) {
                const int n = wn * 64 + j * 16 + l16;
                Xout[row * 256 + n] = (bf16)((acc[i][j][r] - mu) * rstd * gv[j] + bev[j]);
            }
        }
    }
}

// --------------------------------------------------------------------------
// Fused FFN v9 (R15 exact): 64-row tile, grid 1152, 4 waves 1x4,
// 3 blocks/CU. W1P/W2P fragment-order direct, disjoint per wave.
// hc rotated by bits 3-5 of blockIdx. 2 lgkm-only barriers per hc.
// LDS: Xs 32K | Ts 16K (red[64][4] aliases) = 48KB.
// --------------------------------------------------------------------------
__global__ __launch_bounds__(256, 3) void ffn_fused_k(
    const bf16* __restrict__ X,
    const bf16* __restrict__ W1P, const float* __restrict__ b1,
    const bf16* __restrict__ W2P, const float* __restrict__ b2,
    const float* __restrict__ gam, const float* __restrict__ bet,
    bf16* __restrict__ Xout)
{
    __shared__ __align__(16) char smem[49152];
    bf16* Xs = (bf16*)smem;                       // 64 x 256 (32 slots/row)
    bf16* Ts = (bf16*)(smem + 32768);             // 64 x 128 (16 slots/row)
    float2 (*red)[4] = (float2 (*)[4])(void*)(smem + 32768);   // aliases Ts

    const int tid  = threadIdx.x;
    const int lane = tid & 63;
    const int wn   = tid >> 6;          // 0..3: wave's column slice
    const int quad = lane >> 4;
    const int l16  = lane & 15;
    const int bm   = blockIdx.x * 64;
    const int rot  = (blockIdx.x >> 3) & 7;

    // prologue: stage Xs once (the only global_load_lds traffic)
#pragma unroll
    for (int it = 0; it < 8; ++it) {
        const int L = it * 256 + tid;
        const int row = L >> 5, slot = L & 31;
        const int gch = (slot & 24) | ((slot ^ row) & 7);
        async_copy16(X + (size_t)(bm + row) * 256 + gch * 8,
                     (char*)Xs + (size_t)L * 16);
    }
    WAITV0_BAR();

    f32x4 acc2[4][4] = {};

#pragma unroll 1
    for (int hc = 0; hc < 8; ++hc) {
        const int hcr = (hc + rot) & 7;
        float b1v[2];
#pragma unroll
        for (int j = 0; j < 2; ++j)
            b1v[j] = b1[hcr * 128 + wn * 32 + j * 16 + l16];

        f32x4 accA[4][2] = {};

        // ---- phase A: accA = Xs @ W1c^T (wave cols wn*32..+31). No barriers.
#pragma unroll
        for (int q = 0; q < 4; ++q) {
#pragma unroll
            for (int kk = 0; kk < 2; ++kk) {
                const int ch = kk * 4 + quad;
                const int gc = q * 8 + ch;
                bf16x8 af[4], bfr[2];
#pragma unroll
                for (int j = 0; j < 2; ++j)
                    bfr[j] = *(const bf16x8*)(W1P +
                        ((size_t)(((hcr * 4 + q) * 2 + kk) * 8) + wn * 2 + j) * 512
                        + lane * 8);
#pragma unroll
                for (int i = 0; i < 4; ++i) {
                    const int m  = i * 16 + l16;
                    const int sl = (gc & 24) | ((gc ^ m) & 7);
                    af[i] = *(const bf16x8*)((const char*)Xs + (m * 32 + sl) * 16);
                }
                __builtin_amdgcn_s_setprio(1);
#pragma unroll
                for (int i = 0; i < 4; ++i)
#pragma unroll
                    for (int j = 0; j < 2; ++j)
                        accA[i][j] = __builtin_amdgcn_mfma_f32_16x16x32_bf16(
                            af[i], bfr[j], accA[i][j], 0, 0, 0);
                __builtin_amdgcn_s_setprio(0);
            }
        }

        // ---- Ts = relu(accA + b1)  (wave writes cols wn*32..+31)
#pragma unroll
        for (int j = 0; j < 2; ++j) {
            const int h  = wn * 32 + j * 16 + l16;
            const float bb = b1v[j];
            const int g  = h >> 3;
#pragma unroll
            for (int i = 0; i < 4; ++i)
#pragma unroll
                for (int r = 0; r < 4; ++r) {
                    const int m  = i * 16 + quad * 4 + r;
                    const int sl = (g & 8) | ((g ^ m) & 7);
                    const float v = fmaxf(accA[i][j][r] + bb, 0.f);
                    *((bf16*)((char*)Ts + (m * 16 + sl) * 16 + (h & 7) * 2)) = (bf16)v;
                }
        }
        WAITL_BAR();      // Ts writes visible (lgkm only — no vmem drain)

        // ---- phase B: acc2 += Ts @ W2c^T (wave cols wn*64..+63). W2P direct.
#pragma unroll
        for (int q = 0; q < 4; ++q) {
            const int tc = q * 4 + quad;
            bf16x8 af[4], bfr[4];
#pragma unroll
            for (int j = 0; j < 4; ++j)
                bfr[j] = *(const bf16x8*)(W2P +
                    ((size_t)((hcr * 4 + q) * 16) + wn * 4 + j) * 512
                    + lane * 8);
#pragma unroll
            for (int i = 0; i < 4; ++i) {
                const int m  = i * 16 + l16;
                const int sl = (tc & 8) | ((tc ^ m) & 7);
                af[i] = *(const bf16x8*)((const char*)Ts + (m * 16 + sl) * 16);
            }
            __builtin_amdgcn_s_setprio(1);
#pragma unroll
            for (int i = 0; i < 4; ++i)
#pragma unroll
                for (int j = 0; j < 4; ++j)
                    acc2[i][j] = __builtin_amdgcn_mfma_f32_16x16x32_bf16(
                        af[i], bfr[j], acc2[i][j], 0, 0, 0);
            __builtin_amdgcn_s_setprio(0);
        }
        WAITL_BAR();      // phase-B Ts reads done before next hc overwrites
    }

    // ---- epilogue: bias + residual (from Xs) + LayerNorm
    float bv[4], gv[4], bev[4];
#pragma unroll
    for (int j = 0; j < 4; ++j) {
        const int n = wn * 64 + j * 16 + l16;
        bv[j] = b2[n]; gv[j] = gam[n]; bev[j] = bet[n];
    }

#pragma unroll
    for (int i = 0; i < 4; ++i) {
#pragma unroll
        for (int r = 0; r < 4; ++r) {
            const int rl = i * 16 + quad * 4 + r;
            float s1 = 0.f, s2 = 0.f;
#pragma unroll
            for (int j = 0; j < 4; ++j) {
                const int n  = wn * 64 + j * 16 + l16;
                const int gc = n >> 3;
                const int sl = (gc & 24) | ((gc ^ rl) & 7);
                const float xr = (float)*((const bf16*)((const char*)Xs +
                                   (rl * 32 + sl) * 16 + (n & 7) * 2));
                const float v = acc2[i][j][r] + bv[j] + xr;
                acc2[i][j][r] = v;
                s1 += v; s2 += v * v;
            }
#pragma unroll
            for (int off = 1; off < 16; off <<= 1) {
                s1 += __shfl_xor(s1, off, 64);
                s2 += __shfl_xor(s2, off, 64);
            }
            if (l16 == 0) red[rl][wn] = make_float2(s1, s2);
        }
    }
    __syncthreads();

#pragma unroll
    for (int i = 0; i < 4; ++i) {
#pragma unroll
        for (int r = 0; r < 4; ++r) {
            const int rl = i * 16 + quad * 4 + r;
            const float2 p0 = red[rl][0], p1 = red[rl][1];
            const float2 p2 = red[rl][2], p3 = red[rl][3];
            const float mu  = (p0.x + p1.x + p2.x + p3.x) * (1.f / 256.f);
            const float ex2 = (p0.y + p1.y + p2.y + p3.y) * (1.f / 256.f);
            const float rstd = rsqrtf(fmaxf(ex2 - mu * mu, 0.f) + 1e-5f);
            const size_t row = (size_t)(bm + rl);
#pragma unroll
            for (int j = 0; j < 4; ++j) {
                const int n = wn * 64 + j * 16 + l16;
                Xout[row * 256 + n] = (bf16)((acc2[i][j][r] - mu) * rstd * gv[j] + bev[j]);
            }
        }
    }
}

// --------------------------------------------------------------------------
// out[b][c][hw] = sum_e (mean_cam X[p*4+cam][e]) * Wout[c][e] + bout[c]
// --------------------------------------------------------------------------
__global__ __launch_bounds__(256) void out_proj_k(const bf16* __restrict__ X,
                                                  const float* __restrict__ Wout,
                                                  const float* __restrict__ bout,
                                                  float* __restrict__ out)
{
    __shared__ float fused[16][260];
    const int tid = threadIdx.x;
    const int p0  = blockIdx.x * 16;

#pragma unroll
    for (int it = 0; it < 16; ++it) {
        const int idx = it * 256 + tid;
        const int pix = idx >> 8, e = idx & 255;
        const size_t base = (size_t)(p0 + pix) * 1024 + e;
        const float s = (float)X[base] + (float)X[base + 256] +
                        (float)X[base + 512] + (float)X[base + 768];
        fused[pix][e] = s * 0.25f;
    }
    __syncthreads();

    const int pix = tid & 15;
    const int c0  = tid >> 4;
    const int p   = p0 + pix;
    const int b   = p / 9216;
    const int hw  = p % 9216;
#pragma unroll
    for (int it = 0; it < 4; ++it) {
        const int c = it * 16 + c0;
        const float* w = Wout + c * 256;
        float acc = bout[c];
#pragma unroll 8
        for (int e = 0; e < 256; ++e) acc += fused[pix][e] * w[e];
        out[((size_t)b * 64 + c) * 9216 + hw] = acc;
    }
}

// --------------------------------------------------------------------------
extern "C" void kernel_launch(void* const* d_in, const int* in_sizes, int n_in,
                              void* d_out, int out_size, void* d_ws, size_t ws_size,
                              hipStream_t stream)
{
    const float* features = (const float*)d_in[0];
    const float* Wp   = (const float*)d_in[1];
    const float* bp   = (const float*)d_in[2];
    const float* Wqkv = (const float*)d_in[3];
    const float* bqkv = (const float*)d_in[4];
    const float* Wo   = (const float*)d_in[5];
    const float* bo   = (const float*)d_in[6];
    const float* W1   = (const float*)d_in[7];
    const float* b1   = (const float*)d_in[8];
    const float* W2   = (const float*)d_in[9];
    const float* b2   = (const float*)d_in[10];
    const float* g1   = (const float*)d_in[11];
    const float* be1  = (const float*)d_in[12];
    const float* g2   = (const float*)d_in[13];
    const float* be2  = (const float*)d_in[14];
    const float* Wout = (const float*)d_in[15];
    const float* bout = (const float*)d_in[16];
    float* out = (float*)d_out;

    char* ws = (char*)d_ws;
    bf16* X   = (bf16*)(ws);                    // 73728*256
    bf16* QKV = (bf16*)(ws + 37748736ull);      // 73728*768
    bf16* Xf  = (bf16*)(ws + 188743680ull);     // 73728*64
    bf16* WpB = (bf16*)(ws + 198180864ull);     // 256*64
    bf16* Wb  = (bf16*)(ws + 226492416ull);     // packed bf16 weights

    bf16* WqkvB = Wb;                  // 2 x 768*256 (fragment order)
    bf16* WoB   = Wb + 393216;         // 2 x 256*256 (fragment order)
    bf16* W1B   = Wb + 524288;         // 2 x 1024*256 (fragment order)
    bf16* W2B   = Wb + 1048576;        // 2 x 256*1024 (fragment order)

    pack_all_k<<<6208, 256, 0, stream>>>(Wqkv, Wo, W1, W2, Wp,
                                         WqkvB, WoB, W1B, W2B, WpB);

    feat_pack_k<<<dim3(144, 8), 256, 0, stream>>>(features, Xf);
    gemm_bt<false><<<dim3(2, 576), 256, 0, stream>>>(Xf, WpB, bp, X, 256, 64);

    for (int l = 0; l < 2; ++l) {
        gemm_qkv_k<<<dim3(3, 576), 256, 0, stream>>>(
            X, WqkvB + l * 196608, bqkv + l * 768, QKV);
        attn_ln_k<<<1152, 256, 0, stream>>>(
            QKV, WoB + l * 65536, bo + l * 256, X,
            g1 + l * 256, be1 + l * 256, X);
        ffn_fused_k<<<1152, 256, 0, stream>>>(
            X, W1B + l * 262144, b1 + l * 1024,
            W2B + l * 262144, b2 + l * 256,
            g2 + l * 256, be2 + l * 256, X);
    }

    out_proj_k<<<1152, 256, 0, stream>>>(X, Wout, bout, out);
}